// Round 17
// baseline (1361.661 us; speedup 1.0000x reference)
//
#include <hip/hip_runtime.h>
#include <hip/hip_bf16.h>

#define NA 50000
#define NPAP 100000
#define DIN 512
#define DHID 512
#define DOUT 256
#define EAP 400000
#define EPA 400000
#define EAA 200000

typedef unsigned short u16;
typedef __attribute__((ext_vector_type(8))) short bf16x8;
typedef __attribute__((ext_vector_type(4))) float f32x4;

__device__ inline float bflo(unsigned v) { return __uint_as_float(v << 16); }
__device__ inline float bfhi(unsigned v) { return __uint_as_float(v & 0xffff0000u); }
__device__ inline u16 f2bf_rne(float x) {
    unsigned u = __float_as_uint(x);
    return (u16)((u + 0x7FFFu + ((u >> 16) & 1u)) >> 16);
}
__device__ inline unsigned pack2bf(float a, float b) {
    return (unsigned)f2bf_rne(a) | ((unsigned)f2bf_rne(b) << 16);
}

// ---------------- utility kernels ----------------

__global__ void fill_u32_kernel(unsigned* __restrict__ p, unsigned v, int n) {
    int i = blockIdx.x * blockDim.x + threadIdx.x;
    if (i < n) p[i] = v;
}

// Detect whether edge arrays are int64 (high word of every pair-slot zero) or int32.
__global__ void detect_kernel(const unsigned* __restrict__ e, int npairs, int* __restrict__ flag) {
    __shared__ int anyn;
    if (threadIdx.x == 0) anyn = 0;
    __syncthreads();
    unsigned local = 0;
    for (int i = threadIdx.x; i < npairs; i += blockDim.x) local |= e[2 * i + 1];
    if (local) atomicOr(&anyn, 1);
    __syncthreads();
    if (threadIdx.x == 0) flag[0] = (anyn == 0) ? 1 : 0;
}

__device__ inline int edge_at(const void* e, size_t idx, int i64) {
    return i64 ? (int)((const long long*)e)[idx] : ((const int*)e)[idx];
}

// ---------------- B transpose + bf16 hi/lo split, GEMM-tile swizzled layout -------

__global__ void conv_bt_kernel(const float* __restrict__ B, u16* __restrict__ bth,
                               u16* __restrict__ btl, int K, int N) {
    __shared__ float tile[32][33];
    const int nb = blockIdx.x * 32, kb = blockIdx.y * 32;
    const int tx = threadIdx.x, ty = threadIdx.y;
    const int KBLK = K >> 5;
    for (int i = ty; i < 32; i += 8)
        tile[i][tx] = B[(size_t)(kb + i) * N + nb + tx];
    __syncthreads();
    for (int i = ty; i < 32; i += 8) {
        float v = tile[tx][i];  // = B[kb+tx][nb+i] -> n = nb+i, k = kb+tx
        unsigned u = __float_as_uint(v);
        unsigned h = (u + 0x7FFFu + ((u >> 16) & 1u)) >> 16;  // RNE for hi
        float hf = __uint_as_float(h << 16);
        float r = v - hf;                                      // exact residual
        unsigned l = __float_as_uint(r) >> 16;                 // trunc for lo
        const int n = nb + i, k = kb + tx;
        const int nblk = n >> 7, row = n & 127;
        const int kblk = k >> 5, kc = (k & 31) >> 3, ke = k & 7;
        const int cph = kc ^ ((row >> 1) & 3);
        size_t o = (((size_t)(nblk * KBLK + kblk) * 128 + row) << 5) + (cph << 3) + ke;
        bth[o] = (u16)h;
        btl[o] = (u16)l;
    }
}

// ---------------- 2-pass MFMA GEMM (f32 A, on-the-fly RNE): C = A @ B + bias -----
// Register prefetch across the barrier: A(t+1)+B(t+1) issued after barrier2,
// in flight during compute(t). Single-buffer 24 KB LDS, launch_bounds(256,3).

template <bool BF16OUT>
__global__ __launch_bounds__(256, 3) void mfma_gemm_2p_kernel(
    const float* __restrict__ A,
    const u16* __restrict__ Bth, const u16* __restrict__ Btl,
    const float* __restrict__ bias,
    float* __restrict__ C, int M, int N, int K, int gx)
{
    __shared__ u16 Ah[128][32];
    __shared__ u16 Bh[128][32];
    __shared__ u16 Bl[128][32];

    const int nwg = gridDim.x;
    const int bid = blockIdx.x;
    const int qc = nwg >> 3, rc = nwg & 7;
    const int xcd = bid & 7, idx = bid >> 3;
    const int wg = (xcd < rc ? xcd * (qc + 1) : rc * (qc + 1) + (xcd - rc) * qc) + idx;
    const int bx = wg % gx, by = wg / gx;
    const int m0 = by * 128;
    const int n0 = bx * 128;

    const int tid = threadIdx.x;
    const int lane = tid & 63;
    const int wv = tid >> 6;
    const int wm = wv >> 1, wn = wv & 1;
    const int fr = lane & 15;
    const int kg = lane >> 4;

    const int srow = tid >> 1;
    const int oh   = tid & 1;
    const bool a_ok = (m0 + srow) < M;
    const float* Ap = A + (size_t)(m0 + srow) * K + oh * 16;

    const int swc = (srow >> 1) & 3;
    const int p0 = srow * 32 + ((((oh << 1) + 0) ^ swc) << 3);
    const int p1 = srow * 32 + ((((oh << 1) + 1) ^ swc) << 3);
    const int rdc = (kg ^ ((fr >> 1) & 3)) << 3;

    const int KBLK = K >> 5;
    const size_t btile0 = ((size_t)(n0 >> 7) * KBLK) << 12;
    const int bso0 = wv * 512 + lane * 8;
    const int bso1 = (wv + 4) * 512 + lane * 8;

    f32x4 acc[4][4] = {};

    float ar[16];
    uint4 rbh0, rbh1, rbl0, rbl1;

    auto loadregs = [&](int t) {
        const int k0 = t << 5;
        if (a_ok) {
#pragma unroll
            for (int c4 = 0; c4 < 4; ++c4) {
                float4 v = *(const float4*)(Ap + k0 + c4 * 4);
                ar[c4 * 4 + 0] = v.x; ar[c4 * 4 + 1] = v.y;
                ar[c4 * 4 + 2] = v.z; ar[c4 * 4 + 3] = v.w;
            }
        } else {
#pragma unroll
            for (int c = 0; c < 16; ++c) ar[c] = 0.f;
        }
        const u16* bt  = Bth + btile0 + ((size_t)t << 12);
        const u16* blt = Btl + btile0 + ((size_t)t << 12);
        rbh0 = *(const uint4*)(bt + bso0);
        rbh1 = *(const uint4*)(bt + bso1);
        rbl0 = *(const uint4*)(blt + bso0);
        rbl1 = *(const uint4*)(blt + bso1);
    };

    auto storeregs = [&]() {
        uint4 w0 = make_uint4(pack2bf(ar[0], ar[1]), pack2bf(ar[2], ar[3]),
                              pack2bf(ar[4], ar[5]), pack2bf(ar[6], ar[7]));
        uint4 w1 = make_uint4(pack2bf(ar[8], ar[9]), pack2bf(ar[10], ar[11]),
                              pack2bf(ar[12], ar[13]), pack2bf(ar[14], ar[15]));
        u16* ahp = &Ah[0][0];
        *(uint4*)&ahp[p0] = w0;
        *(uint4*)&ahp[p1] = w1;
        u16* bhp = &Bh[0][0];
        u16* blp = &Bl[0][0];
        *(uint4*)&bhp[bso0] = rbh0;
        *(uint4*)&bhp[bso1] = rbh1;
        *(uint4*)&blp[bso0] = rbl0;
        *(uint4*)&blp[bso1] = rbl1;
    };

    loadregs(0);
    const int nt = K >> 5;
    for (int t = 0; t < nt; ++t) {
        __syncthreads();            // barrier1: prior compute done reading LDS
        storeregs();                // pack + ds_write only (~60cy)
        __syncthreads();            // barrier2: stores visible
        if (t + 1 < nt) loadregs(t + 1);  // issue prefetch; hides under MFMAs

        bf16x8 afh[4], bfh[4], bfl[4];
#pragma unroll
        for (int i = 0; i < 4; ++i) {
            const int aoff = (wm * 64 + i * 16 + fr) * 32 + rdc;
            const int boff = (wn * 64 + i * 16 + fr) * 32 + rdc;
            afh[i] = *(const bf16x8*)&Ah[0][aoff];
            bfh[i] = *(const bf16x8*)&Bh[0][boff];
            bfl[i] = *(const bf16x8*)&Bl[0][boff];
        }
#pragma unroll
        for (int i = 0; i < 4; ++i)
#pragma unroll
            for (int j = 0; j < 4; ++j) {
                acc[i][j] = __builtin_amdgcn_mfma_f32_16x16x32_bf16(afh[i], bfh[j], acc[i][j], 0, 0, 0);
                acc[i][j] = __builtin_amdgcn_mfma_f32_16x16x32_bf16(afh[i], bfl[j], acc[i][j], 0, 0, 0);
            }
    }

    // C/D layout: col = lane&15, row = (lane>>4)*4 + reg
#pragma unroll
    for (int j = 0; j < 4; ++j) {
        const int col = n0 + wn * 64 + j * 16 + fr;
        const float bj = bias[col];
#pragma unroll
        for (int i = 0; i < 4; ++i) {
            const int rbase = m0 + wm * 64 + i * 16 + kg * 4;
#pragma unroll
            for (int r = 0; r < 4; ++r) {
                const int grow = rbase + r;
                if (grow < M) {
                    if (BF16OUT)
                        ((u16*)C)[(size_t)grow * N + col] = f2bf_rne(acc[i][j][r] + bj);
                    else
                        C[(size_t)grow * N + col] = acc[i][j][r] + bj;
                }
            }
        }
    }
}

// ---------------- bf16-A MFMA GEMM (2-pass: Ah*Bh + Ah*Bl): C = A @ B + bias -----
// A stored bf16. Register prefetch across the barrier (as above).

template <bool COMB, bool BF16OUT>
__global__ __launch_bounds__(256, 3) void mfma_gemm_bfA_kernel(
    const u16* __restrict__ A, const u16* __restrict__ A2,
    const float* __restrict__ cwp,
    const u16* __restrict__ Bth, const u16* __restrict__ Btl,
    const float* __restrict__ bias,
    float* __restrict__ C, int M, int N, int K, int gx)
{
    __shared__ u16 Ah[128][32];
    __shared__ u16 Bh[128][32];
    __shared__ u16 Bl[128][32];

    const int nwg = gridDim.x;
    const int bid = blockIdx.x;
    const int qc = nwg >> 3, rc = nwg & 7;
    const int xcd = bid & 7, idx = bid >> 3;
    const int wg = (xcd < rc ? xcd * (qc + 1) : rc * (qc + 1) + (xcd - rc) * qc) + idx;
    const int bx = wg % gx, by = wg / gx;
    const int m0 = by * 128;
    const int n0 = bx * 128;

    const int tid = threadIdx.x;
    const int lane = tid & 63;
    const int wv = tid >> 6;
    const int wm = wv >> 1, wn = wv & 1;
    const int fr = lane & 15;
    const int kg = lane >> 4;

    const int srow = tid >> 1;
    const int oh   = tid & 1;
    const bool a_ok = (m0 + srow) < M;
    const u16* Ap  = A + (size_t)(m0 + srow) * K + oh * 16;
    const u16* Ap2 = COMB ? (A2 + (size_t)(m0 + srow) * K + oh * 16) : nullptr;
    float cw0 = 1.f, cw1 = 0.f;
    if (COMB) { cw0 = cwp[0]; cw1 = cwp[1]; }

    const int swc = (srow >> 1) & 3;
    const int p0 = srow * 32 + ((((oh << 1) + 0) ^ swc) << 3);
    const int p1 = srow * 32 + ((((oh << 1) + 1) ^ swc) << 3);
    const int rdc = (kg ^ ((fr >> 1) & 3)) << 3;

    const int KBLK = K >> 5;
    const size_t btile0 = ((size_t)(n0 >> 7) * KBLK) << 12;
    const int bso0 = wv * 512 + lane * 8;
    const int bso1 = (wv + 4) * 512 + lane * 8;

    f32x4 acc[4][4] = {};

    uint4 a0r, a1r, c0r, c1r;
    uint4 rbh0, rbh1, rbl0, rbl1;

    auto loadregs = [&](int t) {
        const int k0 = t << 5;
        a0r = make_uint4(0, 0, 0, 0); a1r = a0r;
        if (a_ok) {
            a0r = *(const uint4*)(Ap + k0);
            a1r = *(const uint4*)(Ap + k0 + 8);
            if (COMB) {
                c0r = *(const uint4*)(Ap2 + k0);
                c1r = *(const uint4*)(Ap2 + k0 + 8);
            }
        } else if (COMB) {
            c0r = make_uint4(0, 0, 0, 0); c1r = c0r;
        }
        const u16* bt  = Bth + btile0 + ((size_t)t << 12);
        const u16* blt = Btl + btile0 + ((size_t)t << 12);
        rbh0 = *(const uint4*)(bt + bso0);
        rbh1 = *(const uint4*)(bt + bso1);
        rbl0 = *(const uint4*)(blt + bso0);
        rbl1 = *(const uint4*)(blt + bso1);
    };

    auto storeregs = [&]() {
        uint4 a0 = a0r, a1 = a1r;
        if (COMB) {
            a0.x = pack2bf(cw0 * bflo(a0r.x) + cw1 * bflo(c0r.x), cw0 * bfhi(a0r.x) + cw1 * bfhi(c0r.x));
            a0.y = pack2bf(cw0 * bflo(a0r.y) + cw1 * bflo(c0r.y), cw0 * bfhi(a0r.y) + cw1 * bfhi(c0r.y));
            a0.z = pack2bf(cw0 * bflo(a0r.z) + cw1 * bflo(c0r.z), cw0 * bfhi(a0r.z) + cw1 * bfhi(c0r.z));
            a0.w = pack2bf(cw0 * bflo(a0r.w) + cw1 * bflo(c0r.w), cw0 * bfhi(a0r.w) + cw1 * bfhi(c0r.w));
            a1.x = pack2bf(cw0 * bflo(a1r.x) + cw1 * bflo(c1r.x), cw0 * bfhi(a1r.x) + cw1 * bfhi(c1r.x));
            a1.y = pack2bf(cw0 * bflo(a1r.y) + cw1 * bflo(c1r.y), cw0 * bfhi(a1r.y) + cw1 * bfhi(c1r.y));
            a1.z = pack2bf(cw0 * bflo(a1r.z) + cw1 * bflo(c1r.z), cw0 * bfhi(a1r.z) + cw1 * bfhi(c1r.z));
            a1.w = pack2bf(cw0 * bflo(a1r.w) + cw1 * bflo(c1r.w), cw0 * bfhi(a1r.w) + cw1 * bfhi(c1r.w));
        }
        u16* ahp = &Ah[0][0];
        *(uint4*)&ahp[p0] = a0;
        *(uint4*)&ahp[p1] = a1;
        u16* bhp = &Bh[0][0];
        u16* blp = &Bl[0][0];
        *(uint4*)&bhp[bso0] = rbh0;
        *(uint4*)&bhp[bso1] = rbh1;
        *(uint4*)&blp[bso0] = rbl0;
        *(uint4*)&blp[bso1] = rbl1;
    };

    loadregs(0);
    const int nt = K >> 5;
    for (int t = 0; t < nt; ++t) {
        __syncthreads();
        storeregs();
        __syncthreads();
        if (t + 1 < nt) loadregs(t + 1);

        bf16x8 afh[4], bfh[4], bfl[4];
#pragma unroll
        for (int i = 0; i < 4; ++i) {
            const int aoff = (wm * 64 + i * 16 + fr) * 32 + rdc;
            const int boff = (wn * 64 + i * 16 + fr) * 32 + rdc;
            afh[i] = *(const bf16x8*)&Ah[0][aoff];
            bfh[i] = *(const bf16x8*)&Bh[0][boff];
            bfl[i] = *(const bf16x8*)&Bl[0][boff];
        }
#pragma unroll
        for (int i = 0; i < 4; ++i)
#pragma unroll
            for (int j = 0; j < 4; ++j) {
                acc[i][j] = __builtin_amdgcn_mfma_f32_16x16x32_bf16(afh[i], bfh[j], acc[i][j], 0, 0, 0);
                acc[i][j] = __builtin_amdgcn_mfma_f32_16x16x32_bf16(afh[i], bfl[j], acc[i][j], 0, 0, 0);
            }
    }

#pragma unroll
    for (int j = 0; j < 4; ++j) {
        const int col = n0 + wn * 64 + j * 16 + fr;
        const float bj = bias[col];
#pragma unroll
        for (int i = 0; i < 4; ++i) {
            const int rbase = m0 + wm * 64 + i * 16 + kg * 4;
#pragma unroll
            for (int r = 0; r < 4; ++r) {
                const int grow = rbase + r;
                if (grow < M) {
                    if (BF16OUT)
                        ((u16*)C)[(size_t)grow * N + col] = f2bf_rne(acc[i][j][r] + bj);
                    else
                        C[(size_t)grow * N + col] = acc[i][j][r] + bj;
                }
            }
        }
    }
}

// ---------------- 1-pass bf16 score GEMM (prefetched) ------------------------------

template <bool BF16A>
__global__ __launch_bounds__(256, 3) void mfma_score1_kernel(
    const void* __restrict__ A_, const u16* __restrict__ Bth,
    const float* __restrict__ bias, int M, int N, int K,
    const float* __restrict__ qv, float* __restrict__ score, int gx)
{
    __shared__ u16 Ah[128][32];
    __shared__ u16 Bh[128][32];

    const int nwg = gridDim.x;
    const int bid = blockIdx.x;
    const int qc = nwg >> 3, rc = nwg & 7;
    const int xcd = bid & 7, idx = bid >> 3;
    const int wg = (xcd < rc ? xcd * (qc + 1) : rc * (qc + 1) + (xcd - rc) * qc) + idx;
    const int bx = wg % gx, by = wg / gx;
    const int m0 = by * 128;
    const int n0 = bx * 128;

    const int tid = threadIdx.x;
    const int lane = tid & 63;
    const int wv = tid >> 6;
    const int wm = wv >> 1, wn = wv & 1;
    const int fr = lane & 15;
    const int kg = lane >> 4;

    const int srow = tid >> 1;
    const int oh   = tid & 1;
    const bool a_ok = (m0 + srow) < M;

    const int swc = (srow >> 1) & 3;
    const int p0 = srow * 32 + ((((oh << 1) + 0) ^ swc) << 3);
    const int p1 = srow * 32 + ((((oh << 1) + 1) ^ swc) << 3);
    const int rdc = (kg ^ ((fr >> 1) & 3)) << 3;

    const int KBLK = K >> 5;
    const size_t btile0 = ((size_t)(n0 >> 7) * KBLK) << 12;
    const int bso0 = wv * 512 + lane * 8;
    const int bso1 = (wv + 4) * 512 + lane * 8;

    f32x4 acc[4][4] = {};

    float arf[16];
    uint4 w0r, w1r;
    uint4 rbh0, rbh1;

    auto loadregs = [&](int t) {
        const int k0 = t << 5;
        if (a_ok) {
            if (BF16A) {
                const u16* Ap = (const u16*)A_ + (size_t)(m0 + srow) * K + oh * 16;
                w0r = *(const uint4*)(Ap + k0);
                w1r = *(const uint4*)(Ap + k0 + 8);
            } else {
                const float* Ap = (const float*)A_ + (size_t)(m0 + srow) * K + oh * 16;
#pragma unroll
                for (int c4 = 0; c4 < 4; ++c4) {
                    float4 v = *(const float4*)(Ap + k0 + c4 * 4);
                    arf[c4 * 4 + 0] = v.x; arf[c4 * 4 + 1] = v.y;
                    arf[c4 * 4 + 2] = v.z; arf[c4 * 4 + 3] = v.w;
                }
            }
        } else {
            if (BF16A) { w0r = make_uint4(0, 0, 0, 0); w1r = w0r; }
            else {
#pragma unroll
                for (int c = 0; c < 16; ++c) arf[c] = 0.f;
            }
        }
        const u16* bt = Bth + btile0 + ((size_t)t << 12);
        rbh0 = *(const uint4*)(bt + bso0);
        rbh1 = *(const uint4*)(bt + bso1);
    };

    auto storeregs = [&]() {
        uint4 w0, w1;
        if (BF16A) { w0 = w0r; w1 = w1r; }
        else {
            w0 = make_uint4(pack2bf(arf[0], arf[1]), pack2bf(arf[2], arf[3]),
                            pack2bf(arf[4], arf[5]), pack2bf(arf[6], arf[7]));
            w1 = make_uint4(pack2bf(arf[8], arf[9]), pack2bf(arf[10], arf[11]),
                            pack2bf(arf[12], arf[13]), pack2bf(arf[14], arf[15]));
        }
        u16* ahp = &Ah[0][0];
        *(uint4*)&ahp[p0] = w0;
        *(uint4*)&ahp[p1] = w1;
        u16* bhp = &Bh[0][0];
        *(uint4*)&bhp[bso0] = rbh0;
        *(uint4*)&bhp[bso1] = rbh1;
    };

    loadregs(0);
    const int nt = K >> 5;
    for (int t = 0; t < nt; ++t) {
        __syncthreads();
        storeregs();
        __syncthreads();
        if (t + 1 < nt) loadregs(t + 1);

        bf16x8 afh[4], bfh[4];
#pragma unroll
        for (int i = 0; i < 4; ++i) {
            afh[i] = *(const bf16x8*)&Ah[0][(wm * 64 + i * 16 + fr) * 32 + rdc];
            bfh[i] = *(const bf16x8*)&Bh[0][(wn * 64 + i * 16 + fr) * 32 + rdc];
        }
#pragma unroll
        for (int i = 0; i < 4; ++i)
#pragma unroll
            for (int j = 0; j < 4; ++j)
                acc[i][j] = __builtin_amdgcn_mfma_f32_16x16x32_bf16(afh[i], bfh[j], acc[i][j], 0, 0, 0);
    }

    float ssum = 0.f;
#pragma unroll
    for (int j = 0; j < 4; ++j) {
        const int col = n0 + wn * 64 + j * 16 + fr;
        const float bj = bias[col];
        const float qj = qv[col];
#pragma unroll
        for (int i = 0; i < 4; ++i) {
            const int rbase = m0 + wm * 64 + i * 16 + kg * 4;
#pragma unroll
            for (int r = 0; r < 4; ++r) {
                if (rbase + r < M) ssum += tanhf(acc[i][j][r] + bj) * qj;
            }
        }
    }
#pragma unroll
    for (int o = 32; o; o >>= 1) ssum += __shfl_xor(ssum, o);
    __syncthreads();
    float* red = (float*)&Ah[0][0];
    if (lane == 0) red[wv] = ssum;
    __syncthreads();
    if (tid == 0) atomicAdd(score, red[0] + red[1] + red[2] + red[3]);
}

// ---------------- per-node attention scores: s_i[n] = h[n,:] . v_i ----------------

template <int NV, bool BF16IN>
__global__ void scores_kernel(const void* __restrict__ h, int n, int D,
                              const float* __restrict__ v0, const float* __restrict__ v1,
                              const float* __restrict__ v2, const float* __restrict__ v3,
                              float* __restrict__ s0, float* __restrict__ s1,
                              float* __restrict__ s2, float* __restrict__ s3)
{
    const int lane = threadIdx.x & 63;
    int wid = (blockIdx.x * blockDim.x + threadIdx.x) >> 6;
    const int nw = (gridDim.x * blockDim.x) >> 6;
    for (int node = wid; node < n; node += nw) {
        float a0 = 0, a1 = 0, a2 = 0, a3 = 0;
        for (int d = lane * 4; d < D; d += 256) {
            float4 x;
            if (BF16IN) {
                const u16* row = (const u16*)h + (size_t)node * D;
                uint2 bv = *(const uint2*)&row[d];
                x = make_float4(bflo(bv.x), bfhi(bv.x), bflo(bv.y), bfhi(bv.y));
            } else {
                const float* row = (const float*)h + (size_t)node * D;
                x = *(const float4*)&row[d];
            }
            float4 w = *(const float4*)&v0[d];
            a0 += x.x * w.x + x.y * w.y + x.z * w.z + x.w * w.w;
            if (NV > 1) { float4 u = *(const float4*)&v1[d]; a1 += x.x * u.x + x.y * u.y + x.z * u.z + x.w * u.w; }
            if (NV > 2) { float4 u = *(const float4*)&v2[d]; a2 += x.x * u.x + x.y * u.y + x.z * u.z + x.w * u.w; }
            if (NV > 3) { float4 u = *(const float4*)&v3[d]; a3 += x.x * u.x + x.y * u.y + x.z * u.z + x.w * u.w; }
        }
#pragma unroll
        for (int o = 32; o; o >>= 1) {
            a0 += __shfl_xor(a0, o);
            if (NV > 1) a1 += __shfl_xor(a1, o);
            if (NV > 2) a2 += __shfl_xor(a2, o);
            if (NV > 3) a3 += __shfl_xor(a3, o);
        }
        if (lane == 0) {
            s0[node] = a0;
            if (NV > 1) s1[node] = a1;
            if (NV > 2) s2[node] = a2;
            if (NV > 3) s3[node] = a3;
        }
    }
}

// ---------------- batched CSR build (all 3 edge types) ----------------------------

__global__ void count3_kernel(const void* __restrict__ eA, const void* __restrict__ eB,
                              const void* __restrict__ eC, const int* __restrict__ flag,
                              int* __restrict__ cA, int* __restrict__ cB, int* __restrict__ cC) {
    int i = blockIdx.x * blockDim.x + threadIdx.x;
    int f = *flag;
    if (i < EAP) {
        atomicAdd(&cA[edge_at(eA, (size_t)EAP + i, f)], 1);
    } else if (i < EAP + EPA) {
        int j = i - EAP;
        atomicAdd(&cB[edge_at(eB, (size_t)EPA + j, f)], 1);
    } else if (i < EAP + EPA + EAA) {
        int j = i - EAP - EPA;
        atomicAdd(&cC[edge_at(eC, (size_t)EAA + j, f)], 1);
    }
}

// parallel 3-phase exclusive scan over the concatenated cnt3 array.

__global__ void scanp1_kernel(const int* __restrict__ cnt, int n, int* __restrict__ part) {
    __shared__ int wsum[16];
    const int base = blockIdx.x * 1024;
    const int t = threadIdx.x, lane = t & 63, w = t >> 6;
    int v = (base + t < n) ? cnt[base + t] : 0;
#pragma unroll
    for (int o = 1; o < 64; o <<= 1) v += __shfl_xor(v, o);
    if (lane == 0) wsum[w] = v;
    __syncthreads();
    if (t == 0) {
        int s = 0;
#pragma unroll
        for (int k = 0; k < 16; ++k) s += wsum[k];
        part[blockIdx.x] = s;
    }
}

__global__ void scanp2_kernel(int* __restrict__ part, int nblk) {
    __shared__ int wsum[16];
    const int t = threadIdx.x, lane = t & 63, w = t >> 6;
    int v = (t < nblk) ? part[t] : 0;
    int x = v;
#pragma unroll
    for (int o = 1; o < 64; o <<= 1) { int y = __shfl_up(x, o); if (lane >= o) x += y; }
    if (lane == 63) wsum[w] = x;
    __syncthreads();
    if (w == 0 && lane < 16) {
        int s = wsum[lane];
#pragma unroll
        for (int o = 1; o < 16; o <<= 1) { int y = __shfl_up(s, o); if (lane >= o) s += y; }
        wsum[lane] = s;
    }
    __syncthreads();
    const int woff = (w > 0) ? wsum[w - 1] : 0;
    if (t < nblk) part[t] = woff + x - v;  // exclusive scan of block sums
}

__global__ void scanp3_kernel(const int* __restrict__ cnt, int n, const int* __restrict__ part,
                              int* __restrict__ offs_ap, int* __restrict__ cur_ap,
                              int* __restrict__ offs_pa, int* __restrict__ cur_pa,
                              int* __restrict__ offs_aa, int* __restrict__ cur_aa) {
    __shared__ int wsum[16];
    const int base = blockIdx.x * 1024;
    const int t = threadIdx.x, lane = t & 63, w = t >> 6;
    int v = (base + t < n) ? cnt[base + t] : 0;
    int x = v;
#pragma unroll
    for (int o = 1; o < 64; o <<= 1) { int y = __shfl_up(x, o); if (lane >= o) x += y; }
    if (lane == 63) wsum[w] = x;
    __syncthreads();
    if (w == 0 && lane < 16) {
        int s = wsum[lane];
#pragma unroll
        for (int o = 1; o < 16; o <<= 1) { int y = __shfl_up(s, o); if (lane >= o) s += y; }
        wsum[lane] = s;
    }
    __syncthreads();
    const int woff = (w > 0) ? wsum[w - 1] : 0;
    const int g = part[blockIdx.x] + woff + x - v;  // global exclusive scan at index i
    const int i = base + t;
    if (i < n) {
        if (i < NPAP)                 { offs_ap[i] = g; cur_ap[i] = g; }
        else if (i == NPAP)           { offs_ap[NPAP] = g; }
        else if (i < NPAP + 1 + NA)   { int j = i - NPAP - 1; int val = g - EAP; offs_pa[j] = val; cur_pa[j] = val; }
        else if (i == NPAP + 1 + NA)  { offs_pa[NA] = g - EAP; }
        else if (i < NPAP + 2 + 2*NA) { int j = i - NPAP - NA - 2; int val = g - EAP - EPA; offs_aa[j] = val; cur_aa[j] = val; }
        else                          { offs_aa[NA] = g - EAP - EPA; }
    }
}

__global__ void scatter3_kernel(const void* __restrict__ eA, const void* __restrict__ eB,
                                const void* __restrict__ eC, const int* __restrict__ flag,
                                int* __restrict__ uA, int* __restrict__ uB, int* __restrict__ uC,
                                int* __restrict__ idA, int* __restrict__ idB, int* __restrict__ idC) {
    int i = blockIdx.x * blockDim.x + threadIdx.x;
    int f = *flag;
    if (i < EAP) {
        int d = edge_at(eA, (size_t)EAP + i, f);
        idA[atomicAdd(&uA[d], 1)] = i;
    } else if (i < EAP + EPA) {
        int j = i - EAP;
        int d = edge_at(eB, (size_t)EPA + j, f);
        idB[atomicAdd(&uB[d], 1)] = j;
    } else if (i < EAP + EPA + EAA) {
        int j = i - EAP - EPA;
        int d = edge_at(eC, (size_t)EAA + j, f);
        idC[atomicAdd(&uC[d], 1)] = j;
    }
}

// ---------------- fully-fused edge attention + CSR aggregation --------------------

template <int DW, bool BF16H, bool BF16OUT>  // DW floats per lane: D/64
__global__ __launch_bounds__(256) void agg_fused_kernel(
    const int* __restrict__ offs, const int* __restrict__ eids,
    const void* __restrict__ e, const int* __restrict__ flag,
    const float* __restrict__ ssrc, const float* __restrict__ sdst,
    const void* __restrict__ hsrc_, void* __restrict__ out,
    int n_dst, int E, int D)
{
    const int lane = threadIdx.x & 63;
    int wid = (blockIdx.x * blockDim.x + threadIdx.x) >> 6;
    const int nw = (gridDim.x * blockDim.x) >> 6;
    const int f = *flag;
    for (int dst = wid; dst < n_dst; dst += nw) {
        const int beg = offs[dst], end = offs[dst + 1];
        const float sd = sdst[dst];

        float dsum = 0.f;
        for (int j = beg + lane; j < end; j += 64) {
            int eid = eids[j];
            float a = ssrc[edge_at(e, eid, f)] + sd;
            a = (a >= 0.f) ? a : 0.2f * a;
            dsum += expf(a);
        }
#pragma unroll
        for (int o = 32; o; o >>= 1) dsum += __shfl_xor(dsum, o);
        const float rden = (end > beg) ? 1.f / dsum : 0.f;

        float acc[DW] = {};
        int j = beg;
        for (; j + 4 <= end; j += 4) {
            const int e0 = eids[j], e1 = eids[j + 1], e2 = eids[j + 2], e3 = eids[j + 3];
            const int q0 = edge_at(e, e0, f), q1 = edge_at(e, e1, f);
            const int q2 = edge_at(e, e2, f), q3 = edge_at(e, e3, f);
            float a0 = ssrc[q0] + sd, a1 = ssrc[q1] + sd;
            float a2 = ssrc[q2] + sd, a3 = ssrc[q3] + sd;
            a0 = (a0 >= 0.f) ? a0 : 0.2f * a0;
            a1 = (a1 >= 0.f) ? a1 : 0.2f * a1;
            a2 = (a2 >= 0.f) ? a2 : 0.2f * a2;
            a3 = (a3 >= 0.f) ? a3 : 0.2f * a3;
            const float w0 = expf(a0) * rden, w1 = expf(a1) * rden;
            const float w2 = expf(a2) * rden, w3 = expf(a3) * rden;
            if (BF16H) {
                const u16* hb = (const u16*)hsrc_;
                const u16* r0 = hb + (size_t)q0 * D + lane * DW;
                const u16* r1 = hb + (size_t)q1 * D + lane * DW;
                const u16* r2 = hb + (size_t)q2 * D + lane * DW;
                const u16* r3 = hb + (size_t)q3 * D + lane * DW;
                if constexpr (DW >= 8) {
#pragma unroll
                    for (int c = 0; c < DW; c += 8) {
                        uint4 b0 = *(const uint4*)&r0[c];
                        uint4 b1 = *(const uint4*)&r1[c];
                        uint4 b2 = *(const uint4*)&r2[c];
                        uint4 b3 = *(const uint4*)&r3[c];
                        acc[c + 0] += bflo(b0.x) * w0 + bflo(b1.x) * w1 + bflo(b2.x) * w2 + bflo(b3.x) * w3;
                        acc[c + 1] += bfhi(b0.x) * w0 + bfhi(b1.x) * w1 + bfhi(b2.x) * w2 + bfhi(b3.x) * w3;
                        acc[c + 2] += bflo(b0.y) * w0 + bflo(b1.y) * w1 + bflo(b2.y) * w2 + bflo(b3.y) * w3;
                        acc[c + 3] += bfhi(b0.y) * w0 + bfhi(b1.y) * w1 + bfhi(b2.y) * w2 + bfhi(b3.y) * w3;
                        acc[c + 4] += bflo(b0.z) * w0 + bflo(b1.z) * w1 + bflo(b2.z) * w2 + bflo(b3.z) * w3;
                        acc[c + 5] += bfhi(b0.z) * w0 + bfhi(b1.z) * w1 + bfhi(b2.z) * w2 + bfhi(b3.z) * w3;
                        acc[c + 6] += bflo(b0.w) * w0 + bflo(b1.w) * w1 + bflo(b2.w) * w2 + bflo(b3.w) * w3;
                        acc[c + 7] += bfhi(b0.w) * w0 + bfhi(b1.w) * w1 + bfhi(b2.w) * w2 + bfhi(b3.w) * w3;
                    }
                } else {
                    uint2 b0 = *(const uint2*)r0;
                    uint2 b1 = *(const uint2*)r1;
                    uint2 b2 = *(const uint2*)r2;
                    uint2 b3 = *(const uint2*)r3;
                    acc[0] += bflo(b0.x) * w0 + bflo(b1.x) * w1 + bflo(b2.x) * w2 + bflo(b3.x) * w3;
                    acc[1] += bfhi(b0.x) * w0 + bfhi(b1.x) * w1 + bfhi(b2.x) * w2 + bfhi(b3.x) * w3;
                    acc[2] += bflo(b0.y) * w0 + bflo(b1.y) * w1 + bflo(b2.y) * w2 + bflo(b3.y) * w3;
                    acc[3] += bfhi(b0.y) * w0 + bfhi(b1.y) * w1 + bfhi(b2.y) * w2 + bfhi(b3.y) * w3;
                }
            } else {
                const float* hf = (const float*)hsrc_;
                const float* r0 = hf + (size_t)q0 * D + lane * DW;
                const float* r1 = hf + (size_t)q1 * D + lane * DW;
                const float* r2 = hf + (size_t)q2 * D + lane * DW;
                const float* r3 = hf + (size_t)q3 * D + lane * DW;
#pragma unroll
                for (int c = 0; c < DW; c += 4) {
                    float4 a0v = *(const float4*)&r0[c];
                    float4 a1v = *(const float4*)&r1[c];
                    float4 a2v = *(const float4*)&r2[c];
                    float4 a3v = *(const float4*)&r3[c];
                    acc[c + 0] += a0v.x * w0 + a1v.x * w1 + a2v.x * w2 + a3v.x * w3;
                    acc[c + 1] += a0v.y * w0 + a1v.y * w1 + a2v.y * w2 + a3v.y * w3;
                    acc[c + 2] += a0v.z * w0 + a1v.z * w1 + a2v.z * w2 + a3v.z * w3;
                    acc[c + 3] += a0v.w * w0 + a1v.w * w1 + a2v.w * w2 + a3v.w * w3;
                }
            }
        }
        for (; j < end; ++j) {
            const int eid = eids[j];
            const int q = edge_at(e, eid, f);
            float a = ssrc[q] + sd;
            a = (a >= 0.f) ? a : 0.2f * a;
            const float w = expf(a) * rden;
            if (BF16H) {
                const u16* row = (const u16*)hsrc_ + (size_t)q * D + lane * DW;
                if constexpr (DW >= 8) {
#pragma unroll
                    for (int c = 0; c < DW; c += 8) {
                        uint4 b0 = *(const uint4*)&row[c];
                        acc[c + 0] += bflo(b0.x) * w; acc[c + 1] += bfhi(b0.x) * w;
                        acc[c + 2] += bflo(b0.y) * w; acc[c + 3] += bfhi(b0.y) * w;
                        acc[c + 4] += bflo(b0.z) * w; acc[c + 5] += bfhi(b0.z) * w;
                        acc[c + 6] += bflo(b0.w) * w; acc[c + 7] += bfhi(b0.w) * w;
                    }
                } else {
                    uint2 b0 = *(const uint2*)row;
                    acc[0] += bflo(b0.x) * w; acc[1] += bfhi(b0.x) * w;
                    acc[2] += bflo(b0.y) * w; acc[3] += bfhi(b0.y) * w;
                }
            } else {
                const float* row = (const float*)hsrc_ + (size_t)q * D + lane * DW;
#pragma unroll
                for (int c = 0; c < DW; c += 4) {
                    float4 v = *(const float4*)&row[c];
                    acc[c + 0] += v.x * w; acc[c + 1] += v.y * w;
                    acc[c + 2] += v.z * w; acc[c + 3] += v.w * w;
                }
            }
        }
        if (BF16OUT) {
            u16* orow = (u16*)out + (size_t)dst * D + lane * DW;
            if constexpr (DW >= 8) {
#pragma unroll
                for (int c = 0; c < DW; c += 8) {
                    uint4 v;
                    v.x = pack2bf(fmaxf(acc[c + 0], 0.f), fmaxf(acc[c + 1], 0.f));
                    v.y = pack2bf(fmaxf(acc[c + 2], 0.f), fmaxf(acc[c + 3], 0.f));
                    v.z = pack2bf(fmaxf(acc[c + 4], 0.f), fmaxf(acc[c + 5], 0.f));
                    v.w = pack2bf(fmaxf(acc[c + 6], 0.f), fmaxf(acc[c + 7], 0.f));
                    *(uint4*)&orow[c] = v;
                }
            } else {
                uint2 v;
                v.x = pack2bf(fmaxf(acc[0], 0.f), fmaxf(acc[1], 0.f));
                v.y = pack2bf(fmaxf(acc[2], 0.f), fmaxf(acc[3], 0.f));
                *(uint2*)orow = v;
            }
        } else {
            float* orow = (float*)out + (size_t)dst * D + lane * DW;
#pragma unroll
            for (int c = 0; c < DW; c += 4) {
                float4 v = make_float4(fmaxf(acc[c + 0], 0.f), fmaxf(acc[c + 1], 0.f),
                                       fmaxf(acc[c + 2], 0.f), fmaxf(acc[c + 3], 0.f));
                *(float4*)&orow[c] = v;
            }
        }
    }
}

// ---------------- semantic attention tail ----------------

__global__ void softmax2_kernel(const float* __restrict__ score, float invN, float* __restrict__ w) {
    if (threadIdx.x == 0 && blockIdx.x == 0) {
        float s0 = score[0] * invN, s1 = score[1] * invN;
        float m = fmaxf(s0, s1);
        float e0 = expf(s0 - m), e1 = expf(s1 - m);
        float r = 1.f / (e0 + e1);
        w[0] = e0 * r;
        w[1] = e1 * r;
    }
}

__global__ void combine2_kernel(const float4* __restrict__ a, const float4* __restrict__ b,
                                const float* __restrict__ w, float4* __restrict__ o, int n4) {
    float w0 = w[0], w1 = w[1];
    for (int i = blockIdx.x * blockDim.x + threadIdx.x; i < n4; i += gridDim.x * blockDim.x) {
        float4 x = a[i], y = b[i];
        o[i] = make_float4(w0 * x.x + w1 * y.x, w0 * x.y + w1 * y.y,
                           w0 * x.z + w1 * y.z, w0 * x.w + w1 * y.w);
    }
}

// ---------------- host orchestration ----------------

extern "C" void kernel_launch(void* const* d_in, const int* in_sizes, int n_in,
                              void* d_out, int out_size, void* d_ws, size_t ws_size,
                              hipStream_t stream) {
    const float* x_a  = (const float*)d_in[0];
    const float* x_p  = (const float*)d_in[1];
    const float* W1   = (const float*)d_in[2];
    const float* b1   = (const float*)d_in[3];
    const float* att1 = (const float*)d_in[4];
    const float* kW1  = (const float*)d_in[5];
    const float* kb1  = (const float*)d_in[6];
    const float* q1   = (const float*)d_in[7];
    const float* W2   = (const float*)d_in[8];
    const float* b2   = (const float*)d_in[9];
    const float* att2 = (const float*)d_in[10];
    const float* kW2  = (const float*)d_in[11];
    const float* kb2  = (const float*)d_in[12];
    const float* q2   = (const float*)d_in[13];
    const void* e_ap  = d_in[14];
    const void* e_pa  = d_in[15];
    const void* e_aa  = d_in[16];
    float* out = (float*)d_out;

    size_t off = 0;
    auto ALLOC = [&](size_t nbytes) -> void* {
        void* p = (char*)d_ws + off;
        off += (nbytes + 255) & ~(size_t)255;
        return p;
    };
    float* bufA = (float*)ALLOC((size_t)NPAP * DHID * 4);  // h_p(bf16, lower) | x2_p(bf16, upper)
    float* bufB = (float*)ALLOC((size_t)NA * DHID * 4);    // h_a(bf16) -> h2a(bf16)
    float* bufC = (float*)ALLOC((size_t)NA * DHID * 4);    // o1(bf16) -> oa1|oa2(f32)
    float* bufD = (float*)ALLOC((size_t)NA * DHID * 4);    // o2(bf16) -> h2p(bf16)
    float* sa_w  = (float*)ALLOC((size_t)NA * 4);
    float* sa_pd = (float*)ALLOC((size_t)NA * 4);
    float* sa_as = (float*)ALLOC((size_t)NA * 4);
    float* sa_ad = (float*)ALLOC((size_t)NA * 4);
    float* sp_wd = (float*)ALLOC((size_t)NPAP * 4);
    float* sp_ps = (float*)ALLOC((size_t)NPAP * 4);
    int* cnt3    = (int*)ALLOC((size_t)(NPAP + 2 * NA + 8) * 4);
    int* scanpart = (int*)ALLOC(256 * 4);
    int* cursor3 = (int*)ALLOC((size_t)(NPAP + 2 * NA + 8) * 4);
    int* offs_ap = (int*)ALLOC((size_t)(NPAP + 1) * 4);
    int* offs_pa = (int*)ALLOC((size_t)(NA + 1) * 4);
    int* offs_aa = (int*)ALLOC((size_t)(NA + 1) * 4);
    int* eids_ap = (int*)ALLOC((size_t)EAP * 4);
    int* eids_pa = (int*)ALLOC((size_t)EPA * 4);
    int* eids_aa = (int*)ALLOC((size_t)EAA * 4);
    const size_t WTOT = 262144u * 3 + 131072u * 2 + 65536u;  // 1,114,112 u16
    u16* w_hi = (u16*)ALLOC(WTOT * 2);
    u16* w_lo = (u16*)ALLOC(WTOT * 2);
    float* score = (float*)ALLOC(8 * 4);
    float* wsem  = (float*)ALLOC(2 * 4);
    int* eflag   = (int*)ALLOC(4);
    if (off > ws_size) return;  // insufficient scratch -> visible failure

    const size_t oW1a = 0, oW1p = 262144, okW1 = 524288;
    const size_t oW2a = 786432, oW2p = 917504, okW2 = 1048576;

    int* cntA = cnt3;
    int* cntB = cnt3 + NPAP + 1;
    int* cntC = cntB + NA + 1;
    int* curA = cursor3;
    int* curB = cursor3 + NPAP + 1;
    int* curC = curB + NA + 1;
    const int CNT3N = NPAP + 2 * NA + 3;

    hipStream_t s = stream;

    detect_kernel<<<1, 256, 0, s>>>((const unsigned*)e_ap, 1024, eflag);

    // ---- one-shot weight conversion (all 6 matrices) ----
    auto conv_b = [&](const float* B_, int K, int N, size_t wo) {
        conv_bt_kernel<<<dim3(N / 32, K / 32), dim3(32, 8), 0, s>>>(B_, w_hi + wo, w_lo + wo, K, N);
    };
    conv_b(W1, DIN, DHID, oW1a);
    conv_b(W1 + (size_t)DIN * DHID, DIN, DHID, oW1p);
    conv_b(kW1, DHID, DHID, okW1);
    conv_b(W2, DHID, DOUT, oW2a);
    conv_b(W2 + (size_t)DHID * DOUT, DHID, DOUT, oW2p);
    conv_b(kW2, DOUT, DOUT, okW2);

    // ---- batched CSR build for all 3 edge types (parallel 3-phase scan) ----
    {
        const int ETOT = EAP + EPA + EAA;
        const int nblk = (CNT3N + 1023) / 1024;  // 196
        fill_u32_kernel<<<(CNT3N + 255) / 256, 256, 0, s>>>((unsigned*)cnt3, 0u, CNT3N);
        count3_kernel<<<(ETOT + 255) / 256, 256, 0, s>>>(e_ap, e_pa, e_aa, eflag, cntA, cntB, cntC);
        scanp1_kernel<<<nblk, 1024, 0, s>>>(cnt3, CNT3N, scanpart);
        scanp2_kernel<<<1, 1024, 0, s>>>(scanpart, nblk);
        scanp3_kernel<<<nblk, 1024, 0, s>>>(cnt3, CNT3N, scanpart,
                                            offs_ap, curA, offs_pa, curB, offs_aa, curC);
        scatter3_kernel<<<(ETOT + 255) / 256, 256, 0, s>>>(e_ap, e_pa, e_aa, eflag,
                                                           curA, curB, curC,
                                                           eids_ap, eids_pa, eids_aa);
    }

    auto gemm_proj_h = [&](const float* A_, size_t wo, const float* bias_, float* C_,
                           int M, int N, int K) {  // f32 A (RNE 2-pass), bf16 C
        int gx = N / 128;
        int nwg = gx * ((M + 127) / 128);
        mfma_gemm_2p_kernel<true><<<nwg, 256, 0, s>>>(A_,
            w_hi + wo, w_lo + wo, bias_, C_, M, N, K, gx);
    };
    auto gemm_proj_bfA_h = [&](const u16* A_, size_t wo, const float* bias_, float* C_,
                               int M, int N, int K) {  // bf16 A, bf16 C
        int gx = N / 128;
        int nwg = gx * ((M + 127) / 128);
        mfma_gemm_bfA_kernel<false, true><<<nwg, 256, 0, s>>>(A_, nullptr, nullptr,
            w_hi + wo, w_lo + wo, bias_, C_, M, N, K, gx);
    };
    auto gemm_proj_bfA_comb_h = [&](const u16* A_, const u16* A2_, const float* cw, size_t wo,
                                    const float* bias_, float* C_, int M, int N, int K) {
        int gx = N / 128;
        int nwg = gx * ((M + 127) / 128);
        mfma_gemm_bfA_kernel<true, true><<<nwg, 256, 0, s>>>(A_, A2_, cw,
            w_hi + wo, w_lo + wo, bias_, C_, M, N, K, gx);
    };
    auto gemm_score_b = [&](const void* A_, size_t wo, const float* bias_, int M, int N, int K,
                            const float* qv, float* sc) {  // bf16 A
        int gx = N / 128;
        int nwg = gx * ((M + 127) / 128);
        mfma_score1_kernel<true><<<nwg, 256, 0, s>>>(A_, w_hi + wo, bias_, M, N, K, qv, sc, gx);
    };
    auto gemm_score_f = [&](const void* A_, size_t wo, const float* bias_, int M, int N, int K,
                            const float* qv, float* sc) {  // f32 A
        int gx = N / 128;
        int nwg = gx * ((M + 127) / 128);
        mfma_score1_kernel<false><<<nwg, 256, 0, s>>>(A_, w_hi + wo, bias_, M, N, K, qv, sc, gx);
    };

    // ---------------- layer 1 (D = 512, h tables + agg outputs bf16) ----------------
    u16* h_a = (u16*)bufB;
    u16* h_p = (u16*)bufA;
    gemm_proj_h(x_a, oW1a, b1, (float*)h_a, NA, DHID, DIN);
    gemm_proj_h(x_p, oW1p, b1 + DHID, (float*)h_p, NPAP, DHID, DIN);

    {
        int ga = (NA + 3) / 4 < 4096 ? (NA + 3) / 4 : 4096;
        int gp = (NPAP + 3) / 4 < 4096 ? (NPAP + 3) / 4 : 4096;
        scores_kernel<4, true><<<ga, 256, 0, s>>>(h_a, NA, DHID,
            att1 + 0 * DHID, att1 + 3 * DHID, att1 + 4 * DHID, att1 + 5 * DHID,
            sa_w, sa_pd, sa_as, sa_ad);
        scores_kernel<2, true><<<gp, 256, 0, s>>>(h_p, NPAP, DHID,
            att1 + 1 * DHID, att1 + 2 * DHID, nullptr, nullptr,
            sp_wd, sp_ps, nullptr, nullptr);
    }

    u16* o1  = (u16*)bufC;   // out_a1, bf16
    u16* o2  = (u16*)bufD;   // out_a2, bf16
    u16* x2p = (u16*)bufA + (size_t)NPAP * DHID;  // out_p, bf16 (upper half of bufA)
    {
        int gw = (NA + 3) / 4;
        agg_fused_kernel<8, true, true><<<gw, 256, 0, s>>>(offs_pa, eids_pa, e_pa, eflag,
            sp_ps, sa_pd, h_p, o1, NA, EPA, DHID);
        agg_fused_kernel<8, true, true><<<gw, 256, 0, s>>>(offs_aa, eids_aa, e_aa, eflag,
            sa_as, sa_ad, h_a, o2, NA, EAA, DHID);
        int gw2 = (NPAP + 3) / 4;
        agg_fused_kernel<8, true, true><<<gw2, 256, 0, s>>>(offs_ap, eids_ap, e_ap, eflag,
            sa_w, sp_wd, h_a, x2p, NPAP, EAP, DHID);
    }

    // L1 semantic: scores + weights only (combine folded into the L2 a-projection)
    fill_u32_kernel<<<1, 64, 0, s>>>((unsigned*)score, 0u, 2);
    gemm_score_b(o1, okW1, kb1, NA, DHID, DHID, q1, &score[0]);
    gemm_score_b(o2, okW1, kb1, NA, DHID, DHID, q1, &score[1]);
    softmax2_kernel<<<1, 64, 0, s>>>(score, 1.f / (float)NA, wsem);

    // ---------------- layer 2 (D = 256, h2 tables bf16) ----------------
    u16* h2a = (u16*)bufB;   // h_a dead (last read: e_ap agg above)
    u16* h2p = (u16*)bufD;   // o2's last read is the COMB projection (stream-ordered)
    gemm_proj_bfA_comb_h(o1, o2, wsem, oW2a, b2, (float*)h2a, NA, DOUT, DHID);
    gemm_proj_bfA_h(x2p, oW2p, b2 + DOUT, (float*)h2p, NPAP, DOUT, DHID);

    {
        int ga = (NA + 3) / 4 < 4096 ? (NA + 3) / 4 : 4096;
        int gp = (NPAP + 3) / 4 < 4096 ? (NPAP + 3) / 4 : 4096;
        scores_kernel<3, true><<<ga, 256, 0, s>>>(h2a, NA, DOUT,
            att2 + 3 * DOUT, att2 + 4 * DOUT, att2 + 5 * DOUT, nullptr,
            sa_pd, sa_as, sa_ad, nullptr);
        scores_kernel<1, true><<<gp, 256, 0, s>>>(h2p, NPAP, DOUT,
            att2 + 2 * DOUT, nullptr, nullptr, nullptr,
            sp_ps, nullptr, nullptr, nullptr);
    }

    float* oa1 = bufC;                       // o1 dead after COMB projection
    float* oa2 = bufC + (size_t)NA * DOUT;
    {
        int gw = (NA + 3) / 4;
        agg_fused_kernel<4, true, false><<<gw, 256, 0, s>>>(offs_pa, eids_pa, e_pa, eflag,
            sp_ps, sa_pd, h2p, oa1, NA, EPA, DOUT);
        agg_fused_kernel<4, true, false><<<gw, 256, 0, s>>>(offs_aa, eids_aa, e_aa, eflag,
            sa_as, sa_ad, h2a, oa2, NA, EAA, DOUT);
    }

    // L2 semantic (final): scores + combine into out
    fill_u32_kernel<<<1, 64, 0, s>>>((unsigned*)score, 0u, 2);
    gemm_score_f(oa1, okW2, kb2, NA, DOUT, DOUT, q2, &score[0]);
    gemm_score_f(oa2, okW2, kb2, NA, DOUT, DOUT, q2, &score[1]);
    softmax2_kernel<<<1, 64, 0, s>>>(score, 1.f / (float)NA, wsem);
    combine2_kernel<<<2048, 256, 0, s>>>((const float4*)oa1, (const float4*)oa2, wsem,
                                         (float4*)out, NA * DOUT / 4);
}

// Round 18
// 1241.561 us; speedup vs baseline: 1.0967x; 1.0967x over previous
//
#include <hip/hip_runtime.h>
#include <hip/hip_bf16.h>

#define NA 50000
#define NPAP 100000
#define DIN 512
#define DHID 512
#define DOUT 256
#define EAP 400000
#define EPA 400000
#define EAA 200000

typedef unsigned short u16;
typedef __attribute__((ext_vector_type(8))) short bf16x8;
typedef __attribute__((ext_vector_type(4))) float f32x4;

__device__ inline float bflo(unsigned v) { return __uint_as_float(v << 16); }
__device__ inline float bfhi(unsigned v) { return __uint_as_float(v & 0xffff0000u); }
__device__ inline u16 f2bf_rne(float x) {
    unsigned u = __float_as_uint(x);
    return (u16)((u + 0x7FFFu + ((u >> 16) & 1u)) >> 16);
}
__device__ inline unsigned pack2bf(float a, float b) {
    return (unsigned)f2bf_rne(a) | ((unsigned)f2bf_rne(b) << 16);
}

// ---------------- utility kernels ----------------

__global__ void fill_u32_kernel(unsigned* __restrict__ p, unsigned v, int n) {
    int i = blockIdx.x * blockDim.x + threadIdx.x;
    if (i < n) p[i] = v;
}

// Detect whether edge arrays are int64 (high word of every pair-slot zero) or int32.
__global__ void detect_kernel(const unsigned* __restrict__ e, int npairs, int* __restrict__ flag) {
    __shared__ int anyn;
    if (threadIdx.x == 0) anyn = 0;
    __syncthreads();
    unsigned local = 0;
    for (int i = threadIdx.x; i < npairs; i += blockDim.x) local |= e[2 * i + 1];
    if (local) atomicOr(&anyn, 1);
    __syncthreads();
    if (threadIdx.x == 0) flag[0] = (anyn == 0) ? 1 : 0;
}

__device__ inline int edge_at(const void* e, size_t idx, int i64) {
    return i64 ? (int)((const long long*)e)[idx] : ((const int*)e)[idx];
}

// ---------------- B transpose + bf16 hi/lo split, GEMM-tile swizzled layout -------

__global__ void conv_bt_kernel(const float* __restrict__ B, u16* __restrict__ bth,
                               u16* __restrict__ btl, int K, int N) {
    __shared__ float tile[32][33];
    const int nb = blockIdx.x * 32, kb = blockIdx.y * 32;
    const int tx = threadIdx.x, ty = threadIdx.y;
    const int KBLK = K >> 5;
    for (int i = ty; i < 32; i += 8)
        tile[i][tx] = B[(size_t)(kb + i) * N + nb + tx];
    __syncthreads();
    for (int i = ty; i < 32; i += 8) {
        float v = tile[tx][i];  // = B[kb+tx][nb+i] -> n = nb+i, k = kb+tx
        unsigned u = __float_as_uint(v);
        unsigned h = (u + 0x7FFFu + ((u >> 16) & 1u)) >> 16;  // RNE for hi
        float hf = __uint_as_float(h << 16);
        float r = v - hf;                                      // exact residual
        unsigned l = __float_as_uint(r) >> 16;                 // trunc for lo
        const int n = nb + i, k = kb + tx;
        const int nblk = n >> 7, row = n & 127;
        const int kblk = k >> 5, kc = (k & 31) >> 3, ke = k & 7;
        const int cph = kc ^ ((row >> 1) & 3);
        size_t o = (((size_t)(nblk * KBLK + kblk) * 128 + row) << 5) + (cph << 3) + ke;
        bth[o] = (u16)h;
        btl[o] = (u16)l;
    }
}

// ---------------- 2-pass MFMA GEMM (f32 A, on-the-fly RNE): C = A @ B + bias -----

template <bool BF16OUT>
__global__ __launch_bounds__(256, 4) void mfma_gemm_2p_kernel(
    const float* __restrict__ A,
    const u16* __restrict__ Bth, const u16* __restrict__ Btl,
    const float* __restrict__ bias,
    float* __restrict__ C, int M, int N, int K, int gx)
{
    __shared__ u16 Ah[128][32];
    __shared__ u16 Bh[128][32];
    __shared__ u16 Bl[128][32];

    const int nwg = gridDim.x;
    const int bid = blockIdx.x;
    const int qc = nwg >> 3, rc = nwg & 7;
    const int xcd = bid & 7, idx = bid >> 3;
    const int wg = (xcd < rc ? xcd * (qc + 1) : rc * (qc + 1) + (xcd - rc) * qc) + idx;
    const int bx = wg % gx, by = wg / gx;
    const int m0 = by * 128;
    const int n0 = bx * 128;

    const int tid = threadIdx.x;
    const int lane = tid & 63;
    const int wv = tid >> 6;
    const int wm = wv >> 1, wn = wv & 1;
    const int fr = lane & 15;
    const int kg = lane >> 4;

    const int srow = tid >> 1;
    const int oh   = tid & 1;
    const bool a_ok = (m0 + srow) < M;
    const float* Ap = A + (size_t)(m0 + srow) * K + oh * 16;

    const int swc = (srow >> 1) & 3;
    const int p0 = srow * 32 + ((((oh << 1) + 0) ^ swc) << 3);
    const int p1 = srow * 32 + ((((oh << 1) + 1) ^ swc) << 3);
    const int rdc = (kg ^ ((fr >> 1) & 3)) << 3;

    const int KBLK = K >> 5;
    const size_t btile0 = ((size_t)(n0 >> 7) * KBLK) << 12;
    const int bso0 = wv * 512 + lane * 8;
    const int bso1 = (wv + 4) * 512 + lane * 8;

    f32x4 acc[4][4] = {};

    const int nt = K >> 5;
    for (int t = 0; t < nt; ++t) {
        __syncthreads();
        {
            const int k0 = t << 5;
            uint4 w0 = make_uint4(0, 0, 0, 0), w1 = w0;
            if (a_ok) {
                float ar[16];
#pragma unroll
                for (int c4 = 0; c4 < 4; ++c4) {
                    float4 v = *(const float4*)(Ap + k0 + c4 * 4);
                    ar[c4 * 4 + 0] = v.x; ar[c4 * 4 + 1] = v.y;
                    ar[c4 * 4 + 2] = v.z; ar[c4 * 4 + 3] = v.w;
                }
                w0 = make_uint4(pack2bf(ar[0], ar[1]), pack2bf(ar[2], ar[3]),
                                pack2bf(ar[4], ar[5]), pack2bf(ar[6], ar[7]));
                w1 = make_uint4(pack2bf(ar[8], ar[9]), pack2bf(ar[10], ar[11]),
                                pack2bf(ar[12], ar[13]), pack2bf(ar[14], ar[15]));
            }
            const u16* bt = Bth + btile0 + ((size_t)t << 12);
            const u16* blt = Btl + btile0 + ((size_t)t << 12);
            uint4 bh0 = *(const uint4*)(bt + bso0);
            uint4 bh1 = *(const uint4*)(bt + bso1);
            uint4 bl0 = *(const uint4*)(blt + bso0);
            uint4 bl1 = *(const uint4*)(blt + bso1);

            u16* ahp = &Ah[0][0];
            *(uint4*)&ahp[p0] = w0;
            *(uint4*)&ahp[p1] = w1;
            u16* bhp = &Bh[0][0];
            u16* blp = &Bl[0][0];
            *(uint4*)&bhp[bso0] = bh0;
            *(uint4*)&bhp[bso1] = bh1;
            *(uint4*)&blp[bso0] = bl0;
            *(uint4*)&blp[bso1] = bl1;
        }
        __syncthreads();

        bf16x8 afh[4], bfh[4], bfl[4];
#pragma unroll
        for (int i = 0; i < 4; ++i) {
            const int aoff = (wm * 64 + i * 16 + fr) * 32 + rdc;
            const int boff = (wn * 64 + i * 16 + fr) * 32 + rdc;
            afh[i] = *(const bf16x8*)&Ah[0][aoff];
            bfh[i] = *(const bf16x8*)&Bh[0][boff];
            bfl[i] = *(const bf16x8*)&Bl[0][boff];
        }
#pragma unroll
        for (int i = 0; i < 4; ++i)
#pragma unroll
            for (int j = 0; j < 4; ++j) {
                acc[i][j] = __builtin_amdgcn_mfma_f32_16x16x32_bf16(afh[i], bfh[j], acc[i][j], 0, 0, 0);
                acc[i][j] = __builtin_amdgcn_mfma_f32_16x16x32_bf16(afh[i], bfl[j], acc[i][j], 0, 0, 0);
            }
    }

    // C/D layout: col = lane&15, row = (lane>>4)*4 + reg
#pragma unroll
    for (int j = 0; j < 4; ++j) {
        const int col = n0 + wn * 64 + j * 16 + fr;
        const float bj = bias[col];
#pragma unroll
        for (int i = 0; i < 4; ++i) {
            const int rbase = m0 + wm * 64 + i * 16 + kg * 4;
#pragma unroll
            for (int r = 0; r < 4; ++r) {
                const int grow = rbase + r;
                if (grow < M) {
                    if (BF16OUT)
                        ((u16*)C)[(size_t)grow * N + col] = f2bf_rne(acc[i][j][r] + bj);
                    else
                        C[(size_t)grow * N + col] = acc[i][j][r] + bj;
                }
            }
        }
    }
}

// ---------------- bf16-A MFMA GEMM (2-pass: Ah*Bh + Ah*Bl): C = A @ B + bias -----
// A stored bf16 row-major. Stage = pure 32B copy (COMB: combine two bf16 A's).

template <bool COMB, bool BF16OUT>
__global__ __launch_bounds__(256, 4) void mfma_gemm_bfA_kernel(
    const u16* __restrict__ A, const u16* __restrict__ A2,
    const float* __restrict__ cwp,
    const u16* __restrict__ Bth, const u16* __restrict__ Btl,
    const float* __restrict__ bias,
    float* __restrict__ C, int M, int N, int K, int gx)
{
    __shared__ u16 Ah[128][32];
    __shared__ u16 Bh[128][32];
    __shared__ u16 Bl[128][32];

    const int nwg = gridDim.x;
    const int bid = blockIdx.x;
    const int qc = nwg >> 3, rc = nwg & 7;
    const int xcd = bid & 7, idx = bid >> 3;
    const int wg = (xcd < rc ? xcd * (qc + 1) : rc * (qc + 1) + (xcd - rc) * qc) + idx;
    const int bx = wg % gx, by = wg / gx;
    const int m0 = by * 128;
    const int n0 = bx * 128;

    const int tid = threadIdx.x;
    const int lane = tid & 63;
    const int wv = tid >> 6;
    const int wm = wv >> 1, wn = wv & 1;
    const int fr = lane & 15;
    const int kg = lane >> 4;

    const int srow = tid >> 1;
    const int oh   = tid & 1;
    const bool a_ok = (m0 + srow) < M;
    const u16* Ap  = A + (size_t)(m0 + srow) * K + oh * 16;
    const u16* Ap2 = COMB ? (A2 + (size_t)(m0 + srow) * K + oh * 16) : nullptr;
    float cw0 = 1.f, cw1 = 0.f;
    if (COMB) { cw0 = cwp[0]; cw1 = cwp[1]; }

    const int swc = (srow >> 1) & 3;
    const int p0 = srow * 32 + ((((oh << 1) + 0) ^ swc) << 3);
    const int p1 = srow * 32 + ((((oh << 1) + 1) ^ swc) << 3);
    const int rdc = (kg ^ ((fr >> 1) & 3)) << 3;

    const int KBLK = K >> 5;
    const size_t btile0 = ((size_t)(n0 >> 7) * KBLK) << 12;
    const int bso0 = wv * 512 + lane * 8;
    const int bso1 = (wv + 4) * 512 + lane * 8;

    f32x4 acc[4][4] = {};

    const int nt = K >> 5;
    for (int t = 0; t < nt; ++t) {
        __syncthreads();
        {
            const int k0 = t << 5;
            uint4 a0 = make_uint4(0, 0, 0, 0), a1 = a0;
            if (a_ok) {
                a0 = *(const uint4*)(Ap + k0);
                a1 = *(const uint4*)(Ap + k0 + 8);
                if (COMB) {
                    uint4 c0 = *(const uint4*)(Ap2 + k0);
                    uint4 c1 = *(const uint4*)(Ap2 + k0 + 8);
                    a0.x = pack2bf(cw0 * bflo(a0.x) + cw1 * bflo(c0.x), cw0 * bfhi(a0.x) + cw1 * bfhi(c0.x));
                    a0.y = pack2bf(cw0 * bflo(a0.y) + cw1 * bflo(c0.y), cw0 * bfhi(a0.y) + cw1 * bfhi(c0.y));
                    a0.z = pack2bf(cw0 * bflo(a0.z) + cw1 * bflo(c0.z), cw0 * bfhi(a0.z) + cw1 * bfhi(c0.z));
                    a0.w = pack2bf(cw0 * bflo(a0.w) + cw1 * bflo(c0.w), cw0 * bfhi(a0.w) + cw1 * bfhi(c0.w));
                    a1.x = pack2bf(cw0 * bflo(a1.x) + cw1 * bflo(c1.x), cw0 * bfhi(a1.x) + cw1 * bfhi(c1.x));
                    a1.y = pack2bf(cw0 * bflo(a1.y) + cw1 * bflo(c1.y), cw0 * bfhi(a1.y) + cw1 * bfhi(c1.y));
                    a1.z = pack2bf(cw0 * bflo(a1.z) + cw1 * bflo(c1.z), cw0 * bfhi(a1.z) + cw1 * bfhi(c1.z));
                    a1.w = pack2bf(cw0 * bflo(a1.w) + cw1 * bflo(c1.w), cw0 * bfhi(a1.w) + cw1 * bfhi(c1.w));
                }
            }
            const u16* bt = Bth + btile0 + ((size_t)t << 12);
            const u16* blt = Btl + btile0 + ((size_t)t << 12);
            uint4 bh0 = *(const uint4*)(bt + bso0);
            uint4 bh1 = *(const uint4*)(bt + bso1);
            uint4 bl0 = *(const uint4*)(blt + bso0);
            uint4 bl1 = *(const uint4*)(blt + bso1);

            u16* ahp = &Ah[0][0];
            *(uint4*)&ahp[p0] = a0;
            *(uint4*)&ahp[p1] = a1;
            u16* bhp = &Bh[0][0];
            u16* blp = &Bl[0][0];
            *(uint4*)&bhp[bso0] = bh0;
            *(uint4*)&bhp[bso1] = bh1;
            *(uint4*)&blp[bso0] = bl0;
            *(uint4*)&blp[bso1] = bl1;
        }
        __syncthreads();

        bf16x8 afh[4], bfh[4], bfl[4];
#pragma unroll
        for (int i = 0; i < 4; ++i) {
            const int aoff = (wm * 64 + i * 16 + fr) * 32 + rdc;
            const int boff = (wn * 64 + i * 16 + fr) * 32 + rdc;
            afh[i] = *(const bf16x8*)&Ah[0][aoff];
            bfh[i] = *(const bf16x8*)&Bh[0][boff];
            bfl[i] = *(const bf16x8*)&Bl[0][boff];
        }
#pragma unroll
        for (int i = 0; i < 4; ++i)
#pragma unroll
            for (int j = 0; j < 4; ++j) {
                acc[i][j] = __builtin_amdgcn_mfma_f32_16x16x32_bf16(afh[i], bfh[j], acc[i][j], 0, 0, 0);
                acc[i][j] = __builtin_amdgcn_mfma_f32_16x16x32_bf16(afh[i], bfl[j], acc[i][j], 0, 0, 0);
            }
    }

#pragma unroll
    for (int j = 0; j < 4; ++j) {
        const int col = n0 + wn * 64 + j * 16 + fr;
        const float bj = bias[col];
#pragma unroll
        for (int i = 0; i < 4; ++i) {
            const int rbase = m0 + wm * 64 + i * 16 + kg * 4;
#pragma unroll
            for (int r = 0; r < 4; ++r) {
                const int grow = rbase + r;
                if (grow < M) {
                    if (BF16OUT)
                        ((u16*)C)[(size_t)grow * N + col] = f2bf_rne(acc[i][j][r] + bj);
                    else
                        C[(size_t)grow * N + col] = acc[i][j][r] + bj;
                }
            }
        }
    }
}

// ---------------- 1-pass bf16 score GEMM ------------------------------------------

template <bool BF16A>
__global__ __launch_bounds__(256, 4) void mfma_score1_kernel(
    const void* __restrict__ A_, const u16* __restrict__ Bth,
    const float* __restrict__ bias, int M, int N, int K,
    const float* __restrict__ qv, float* __restrict__ score, int gx)
{
    __shared__ u16 Ah[128][32];
    __shared__ u16 Bh[128][32];

    const int nwg = gridDim.x;
    const int bid = blockIdx.x;
    const int qc = nwg >> 3, rc = nwg & 7;
    const int xcd = bid & 7, idx = bid >> 3;
    const int wg = (xcd < rc ? xcd * (qc + 1) : rc * (qc + 1) + (xcd - rc) * qc) + idx;
    const int bx = wg % gx, by = wg / gx;
    const int m0 = by * 128;
    const int n0 = bx * 128;

    const int tid = threadIdx.x;
    const int lane = tid & 63;
    const int wv = tid >> 6;
    const int wm = wv >> 1, wn = wv & 1;
    const int fr = lane & 15;
    const int kg = lane >> 4;

    const int srow = tid >> 1;
    const int oh   = tid & 1;
    const bool a_ok = (m0 + srow) < M;

    const int swc = (srow >> 1) & 3;
    const int p0 = srow * 32 + ((((oh << 1) + 0) ^ swc) << 3);
    const int p1 = srow * 32 + ((((oh << 1) + 1) ^ swc) << 3);
    const int rdc = (kg ^ ((fr >> 1) & 3)) << 3;

    const int KBLK = K >> 5;
    const size_t btile0 = ((size_t)(n0 >> 7) * KBLK) << 12;
    const int bso0 = wv * 512 + lane * 8;
    const int bso1 = (wv + 4) * 512 + lane * 8;

    f32x4 acc[4][4] = {};

    const int nt = K >> 5;
    for (int t = 0; t < nt; ++t) {
        __syncthreads();
        {
            const int k0 = t << 5;
            uint4 w0 = make_uint4(0, 0, 0, 0), w1 = w0;
            if (a_ok) {
                if (BF16A) {
                    const u16* Ap = (const u16*)A_ + (size_t)(m0 + srow) * K + oh * 16;
                    w0 = *(const uint4*)(Ap + k0);
                    w1 = *(const uint4*)(Ap + k0 + 8);
                } else {
                    const float* Ap = (const float*)A_ + (size_t)(m0 + srow) * K + oh * 16;
                    float ar[16];
#pragma unroll
                    for (int c4 = 0; c4 < 4; ++c4) {
                        float4 v = *(const float4*)(Ap + k0 + c4 * 4);
                        ar[c4 * 4 + 0] = v.x; ar[c4 * 4 + 1] = v.y;
                        ar[c4 * 4 + 2] = v.z; ar[c4 * 4 + 3] = v.w;
                    }
                    w0 = make_uint4(pack2bf(ar[0], ar[1]), pack2bf(ar[2], ar[3]),
                                    pack2bf(ar[4], ar[5]), pack2bf(ar[6], ar[7]));
                    w1 = make_uint4(pack2bf(ar[8], ar[9]), pack2bf(ar[10], ar[11]),
                                    pack2bf(ar[12], ar[13]), pack2bf(ar[14], ar[15]));
                }
            }
            const u16* bt = Bth + btile0 + ((size_t)t << 12);
            uint4 bh0 = *(const uint4*)(bt + bso0);
            uint4 bh1 = *(const uint4*)(bt + bso1);
            u16* ahp = &Ah[0][0];
            *(uint4*)&ahp[p0] = w0;
            *(uint4*)&ahp[p1] = w1;
            u16* bhp = &Bh[0][0];
            *(uint4*)&bhp[bso0] = bh0;
            *(uint4*)&bhp[bso1] = bh1;
        }
        __syncthreads();

        bf16x8 afh[4], bfh[4];
#pragma unroll
        for (int i = 0; i < 4; ++i) {
            afh[i] = *(const bf16x8*)&Ah[0][(wm * 64 + i * 16 + fr) * 32 + rdc];
            bfh[i] = *(const bf16x8*)&Bh[0][(wn * 64 + i * 16 + fr) * 32 + rdc];
        }
#pragma unroll
        for (int i = 0; i < 4; ++i)
#pragma unroll
            for (int j = 0; j < 4; ++j)
                acc[i][j] = __builtin_amdgcn_mfma_f32_16x16x32_bf16(afh[i], bfh[j], acc[i][j], 0, 0, 0);
    }

    float ssum = 0.f;
#pragma unroll
    for (int j = 0; j < 4; ++j) {
        const int col = n0 + wn * 64 + j * 16 + fr;
        const float bj = bias[col];
        const float qj = qv[col];
#pragma unroll
        for (int i = 0; i < 4; ++i) {
            const int rbase = m0 + wm * 64 + i * 16 + kg * 4;
#pragma unroll
            for (int r = 0; r < 4; ++r) {
                if (rbase + r < M) ssum += tanhf(acc[i][j][r] + bj) * qj;
            }
        }
    }
#pragma unroll
    for (int o = 32; o; o >>= 1) ssum += __shfl_xor(ssum, o);
    __syncthreads();
    float* red = (float*)&Ah[0][0];
    if (lane == 0) red[wv] = ssum;
    __syncthreads();
    if (tid == 0) atomicAdd(score, red[0] + red[1] + red[2] + red[3]);
}

// ---------------- per-node attention scores: s_i[n] = h[n,:] . v_i ----------------

template <int NV, bool BF16IN>
__global__ void scores_kernel(const void* __restrict__ h, int n, int D,
                              const float* __restrict__ v0, const float* __restrict__ v1,
                              const float* __restrict__ v2, const float* __restrict__ v3,
                              float* __restrict__ s0, float* __restrict__ s1,
                              float* __restrict__ s2, float* __restrict__ s3)
{
    const int lane = threadIdx.x & 63;
    int wid = (blockIdx.x * blockDim.x + threadIdx.x) >> 6;
    const int nw = (gridDim.x * blockDim.x) >> 6;
    for (int node = wid; node < n; node += nw) {
        float a0 = 0, a1 = 0, a2 = 0, a3 = 0;
        for (int d = lane * 4; d < D; d += 256) {
            float4 x;
            if (BF16IN) {
                const u16* row = (const u16*)h + (size_t)node * D;
                uint2 bv = *(const uint2*)&row[d];
                x = make_float4(bflo(bv.x), bfhi(bv.x), bflo(bv.y), bfhi(bv.y));
            } else {
                const float* row = (const float*)h + (size_t)node * D;
                x = *(const float4*)&row[d];
            }
            float4 w = *(const float4*)&v0[d];
            a0 += x.x * w.x + x.y * w.y + x.z * w.z + x.w * w.w;
            if (NV > 1) { float4 u = *(const float4*)&v1[d]; a1 += x.x * u.x + x.y * u.y + x.z * u.z + x.w * u.w; }
            if (NV > 2) { float4 u = *(const float4*)&v2[d]; a2 += x.x * u.x + x.y * u.y + x.z * u.z + x.w * u.w; }
            if (NV > 3) { float4 u = *(const float4*)&v3[d]; a3 += x.x * u.x + x.y * u.y + x.z * u.z + x.w * u.w; }
        }
#pragma unroll
        for (int o = 32; o; o >>= 1) {
            a0 += __shfl_xor(a0, o);
            if (NV > 1) a1 += __shfl_xor(a1, o);
            if (NV > 2) a2 += __shfl_xor(a2, o);
            if (NV > 3) a3 += __shfl_xor(a3, o);
        }
        if (lane == 0) {
            s0[node] = a0;
            if (NV > 1) s1[node] = a1;
            if (NV > 2) s2[node] = a2;
            if (NV > 3) s3[node] = a3;
        }
    }
}

// ---------------- batched CSR build (all 3 edge types) ----------------------------

__global__ void count3_kernel(const void* __restrict__ eA, const void* __restrict__ eB,
                              const void* __restrict__ eC, const int* __restrict__ flag,
                              int* __restrict__ cA, int* __restrict__ cB, int* __restrict__ cC) {
    int i = blockIdx.x * blockDim.x + threadIdx.x;
    int f = *flag;
    if (i < EAP) {
        atomicAdd(&cA[edge_at(eA, (size_t)EAP + i, f)], 1);
    } else if (i < EAP + EPA) {
        int j = i - EAP;
        atomicAdd(&cB[edge_at(eB, (size_t)EPA + j, f)], 1);
    } else if (i < EAP + EPA + EAA) {
        int j = i - EAP - EPA;
        atomicAdd(&cC[edge_at(eC, (size_t)EAA + j, f)], 1);
    }
}

// parallel 3-phase exclusive scan over the concatenated cnt3 array.

__global__ void scanp1_kernel(const int* __restrict__ cnt, int n, int* __restrict__ part) {
    __shared__ int wsum[16];
    const int base = blockIdx.x * 1024;
    const int t = threadIdx.x, lane = t & 63, w = t >> 6;
    int v = (base + t < n) ? cnt[base + t] : 0;
#pragma unroll
    for (int o = 1; o < 64; o <<= 1) v += __shfl_xor(v, o);
    if (lane == 0) wsum[w] = v;
    __syncthreads();
    if (t == 0) {
        int s = 0;
#pragma unroll
        for (int k = 0; k < 16; ++k) s += wsum[k];
        part[blockIdx.x] = s;
    }
}

__global__ void scanp2_kernel(int* __restrict__ part, int nblk) {
    __shared__ int wsum[16];
    const int t = threadIdx.x, lane = t & 63, w = t >> 6;
    int v = (t < nblk) ? part[t] : 0;
    int x = v;
#pragma unroll
    for (int o = 1; o < 64; o <<= 1) { int y = __shfl_up(x, o); if (lane >= o) x += y; }
    if (lane == 63) wsum[w] = x;
    __syncthreads();
    if (w == 0 && lane < 16) {
        int s = wsum[lane];
#pragma unroll
        for (int o = 1; o < 16; o <<= 1) { int y = __shfl_up(s, o); if (lane >= o) s += y; }
        wsum[lane] = s;
    }
    __syncthreads();
    const int woff = (w > 0) ? wsum[w - 1] : 0;
    if (t < nblk) part[t] = woff + x - v;  // exclusive scan of block sums
}

__global__ void scanp3_kernel(const int* __restrict__ cnt, int n, const int* __restrict__ part,
                              int* __restrict__ offs_ap, int* __restrict__ cur_ap,
                              int* __restrict__ offs_pa, int* __restrict__ cur_pa,
                              int* __restrict__ offs_aa, int* __restrict__ cur_aa) {
    __shared__ int wsum[16];
    const int base = blockIdx.x * 1024;
    const int t = threadIdx.x, lane = t & 63, w = t >> 6;
    int v = (base + t < n) ? cnt[base + t] : 0;
    int x = v;
#pragma unroll
    for (int o = 1; o < 64; o <<= 1) { int y = __shfl_up(x, o); if (lane >= o) x += y; }
    if (lane == 63) wsum[w] = x;
    __syncthreads();
    if (w == 0 && lane < 16) {
        int s = wsum[lane];
#pragma unroll
        for (int o = 1; o < 16; o <<= 1) { int y = __shfl_up(s, o); if (lane >= o) s += y; }
        wsum[lane] = s;
    }
    __syncthreads();
    const int woff = (w > 0) ? wsum[w - 1] : 0;
    const int g = part[blockIdx.x] + woff + x - v;  // global exclusive scan at index i
    const int i = base + t;
    if (i < n) {
        if (i < NPAP)                 { offs_ap[i] = g; cur_ap[i] = g; }
        else if (i == NPAP)           { offs_ap[NPAP] = g; }
        else if (i < NPAP + 1 + NA)   { int j = i - NPAP - 1; int val = g - EAP; offs_pa[j] = val; cur_pa[j] = val; }
        else if (i == NPAP + 1 + NA)  { offs_pa[NA] = g - EAP; }
        else if (i < NPAP + 2 + 2*NA) { int j = i - NPAP - NA - 2; int val = g - EAP - EPA; offs_aa[j] = val; cur_aa[j] = val; }
        else                          { offs_aa[NA] = g - EAP - EPA; }
    }
}

__global__ void scatter3_kernel(const void* __restrict__ eA, const void* __restrict__ eB,
                                const void* __restrict__ eC, const int* __restrict__ flag,
                                int* __restrict__ uA, int* __restrict__ uB, int* __restrict__ uC,
                                int* __restrict__ idA, int* __restrict__ idB, int* __restrict__ idC) {
    int i = blockIdx.x * blockDim.x + threadIdx.x;
    int f = *flag;
    if (i < EAP) {
        int d = edge_at(eA, (size_t)EAP + i, f);
        idA[atomicAdd(&uA[d], 1)] = i;
    } else if (i < EAP + EPA) {
        int j = i - EAP;
        int d = edge_at(eB, (size_t)EPA + j, f);
        idB[atomicAdd(&uB[d], 1)] = j;
    } else if (i < EAP + EPA + EAA) {
        int j = i - EAP - EPA;
        int d = edge_at(eC, (size_t)EAA + j, f);
        idC[atomicAdd(&uC[d], 1)] = j;
    }
}

// ---------------- fully-fused edge attention + CSR aggregation --------------------

template <int DW, bool BF16H, bool BF16OUT>  // DW floats per lane: D/64
__global__ __launch_bounds__(256) void agg_fused_kernel(
    const int* __restrict__ offs, const int* __restrict__ eids,
    const void* __restrict__ e, const int* __restrict__ flag,
    const float* __restrict__ ssrc, const float* __restrict__ sdst,
    const void* __restrict__ hsrc_, void* __restrict__ out,
    int n_dst, int E, int D)
{
    const int lane = threadIdx.x & 63;
    int wid = (blockIdx.x * blockDim.x + threadIdx.x) >> 6;
    const int nw = (gridDim.x * blockDim.x) >> 6;
    const int f = *flag;
    for (int dst = wid; dst < n_dst; dst += nw) {
        const int beg = offs[dst], end = offs[dst + 1];
        const float sd = sdst[dst];

        float dsum = 0.f;
        for (int j = beg + lane; j < end; j += 64) {
            int eid = eids[j];
            float a = ssrc[edge_at(e, eid, f)] + sd;
            a = (a >= 0.f) ? a : 0.2f * a;
            dsum += expf(a);
        }
#pragma unroll
        for (int o = 32; o; o >>= 1) dsum += __shfl_xor(dsum, o);
        const float rden = (end > beg) ? 1.f / dsum : 0.f;

        float acc[DW] = {};
        int j = beg;
        for (; j + 4 <= end; j += 4) {
            const int e0 = eids[j], e1 = eids[j + 1], e2 = eids[j + 2], e3 = eids[j + 3];
            const int q0 = edge_at(e, e0, f), q1 = edge_at(e, e1, f);
            const int q2 = edge_at(e, e2, f), q3 = edge_at(e, e3, f);
            float a0 = ssrc[q0] + sd, a1 = ssrc[q1] + sd;
            float a2 = ssrc[q2] + sd, a3 = ssrc[q3] + sd;
            a0 = (a0 >= 0.f) ? a0 : 0.2f * a0;
            a1 = (a1 >= 0.f) ? a1 : 0.2f * a1;
            a2 = (a2 >= 0.f) ? a2 : 0.2f * a2;
            a3 = (a3 >= 0.f) ? a3 : 0.2f * a3;
            const float w0 = expf(a0) * rden, w1 = expf(a1) * rden;
            const float w2 = expf(a2) * rden, w3 = expf(a3) * rden;
            if (BF16H) {
                const u16* hb = (const u16*)hsrc_;
                const u16* r0 = hb + (size_t)q0 * D + lane * DW;
                const u16* r1 = hb + (size_t)q1 * D + lane * DW;
                const u16* r2 = hb + (size_t)q2 * D + lane * DW;
                const u16* r3 = hb + (size_t)q3 * D + lane * DW;
                if constexpr (DW >= 8) {
#pragma unroll
                    for (int c = 0; c < DW; c += 8) {
                        uint4 b0 = *(const uint4*)&r0[c];
                        uint4 b1 = *(const uint4*)&r1[c];
                        uint4 b2 = *(const uint4*)&r2[c];
                        uint4 b3 = *(const uint4*)&r3[c];
                        acc[c + 0] += bflo(b0.x) * w0 + bflo(b1.x) * w1 + bflo(b2.x) * w2 + bflo(b3.x) * w3;
                        acc[c + 1] += bfhi(b0.x) * w0 + bfhi(b1.x) * w1 + bfhi(b2.x) * w2 + bfhi(b3.x) * w3;
                        acc[c + 2] += bflo(b0.y) * w0 + bflo(b1.y) * w1 + bflo(b2.y) * w2 + bflo(b3.y) * w3;
                        acc[c + 3] += bfhi(b0.y) * w0 + bfhi(b1.y) * w1 + bfhi(b2.y) * w2 + bfhi(b3.y) * w3;
                        acc[c + 4] += bflo(b0.z) * w0 + bflo(b1.z) * w1 + bflo(b2.z) * w2 + bflo(b3.z) * w3;
                        acc[c + 5] += bfhi(b0.z) * w0 + bfhi(b1.z) * w1 + bfhi(b2.z) * w2 + bfhi(b3.z) * w3;
                        acc[c + 6] += bflo(b0.w) * w0 + bflo(b1.w) * w1 + bflo(b2.w) * w2 + bflo(b3.w) * w3;
                        acc[c + 7] += bfhi(b0.w) * w0 + bfhi(b1.w) * w1 + bfhi(b2.w) * w2 + bfhi(b3.w) * w3;
                    }
                } else {
                    uint2 b0 = *(const uint2*)r0;
                    uint2 b1 = *(const uint2*)r1;
                    uint2 b2 = *(const uint2*)r2;
                    uint2 b3 = *(const uint2*)r3;
                    acc[0] += bflo(b0.x) * w0 + bflo(b1.x) * w1 + bflo(b2.x) * w2 + bflo(b3.x) * w3;
                    acc[1] += bfhi(b0.x) * w0 + bfhi(b1.x) * w1 + bfhi(b2.x) * w2 + bfhi(b3.x) * w3;
                    acc[2] += bflo(b0.y) * w0 + bflo(b1.y) * w1 + bflo(b2.y) * w2 + bflo(b3.y) * w3;
                    acc[3] += bfhi(b0.y) * w0 + bfhi(b1.y) * w1 + bfhi(b2.y) * w2 + bfhi(b3.y) * w3;
                }
            } else {
                const float* hf = (const float*)hsrc_;
                const float* r0 = hf + (size_t)q0 * D + lane * DW;
                const float* r1 = hf + (size_t)q1 * D + lane * DW;
                const float* r2 = hf + (size_t)q2 * D + lane * DW;
                const float* r3 = hf + (size_t)q3 * D + lane * DW;
#pragma unroll
                for (int c = 0; c < DW; c += 4) {
                    float4 a0v = *(const float4*)&r0[c];
                    float4 a1v = *(const float4*)&r1[c];
                    float4 a2v = *(const float4*)&r2[c];
                    float4 a3v = *(const float4*)&r3[c];
                    acc[c + 0] += a0v.x * w0 + a1v.x * w1 + a2v.x * w2 + a3v.x * w3;
                    acc[c + 1] += a0v.y * w0 + a1v.y * w1 + a2v.y * w2 + a3v.y * w3;
                    acc[c + 2] += a0v.z * w0 + a1v.z * w1 + a2v.z * w2 + a3v.z * w3;
                    acc[c + 3] += a0v.w * w0 + a1v.w * w1 + a2v.w * w2 + a3v.w * w3;
                }
            }
        }
        for (; j < end; ++j) {
            const int eid = eids[j];
            const int q = edge_at(e, eid, f);
            float a = ssrc[q] + sd;
            a = (a >= 0.f) ? a : 0.2f * a;
            const float w = expf(a) * rden;
            if (BF16H) {
                const u16* row = (const u16*)hsrc_ + (size_t)q * D + lane * DW;
                if constexpr (DW >= 8) {
#pragma unroll
                    for (int c = 0; c < DW; c += 8) {
                        uint4 b0 = *(const uint4*)&row[c];
                        acc[c + 0] += bflo(b0.x) * w; acc[c + 1] += bfhi(b0.x) * w;
                        acc[c + 2] += bflo(b0.y) * w; acc[c + 3] += bfhi(b0.y) * w;
                        acc[c + 4] += bflo(b0.z) * w; acc[c + 5] += bfhi(b0.z) * w;
                        acc[c + 6] += bflo(b0.w) * w; acc[c + 7] += bfhi(b0.w) * w;
                    }
                } else {
                    uint2 b0 = *(const uint2*)row;
                    acc[0] += bflo(b0.x) * w; acc[1] += bfhi(b0.x) * w;
                    acc[2] += bflo(b0.y) * w; acc[3] += bfhi(b0.y) * w;
                }
            } else {
                const float* row = (const float*)hsrc_ + (size_t)q * D + lane * DW;
#pragma unroll
                for (int c = 0; c < DW; c += 4) {
                    float4 v = *(const float4*)&row[c];
                    acc[c + 0] += v.x * w; acc[c + 1] += v.y * w;
                    acc[c + 2] += v.z * w; acc[c + 3] += v.w * w;
                }
            }
        }
        if (BF16OUT) {
            u16* orow = (u16*)out + (size_t)dst * D + lane * DW;
            if constexpr (DW >= 8) {
#pragma unroll
                for (int c = 0; c < DW; c += 8) {
                    uint4 v;
                    v.x = pack2bf(fmaxf(acc[c + 0], 0.f), fmaxf(acc[c + 1], 0.f));
                    v.y = pack2bf(fmaxf(acc[c + 2], 0.f), fmaxf(acc[c + 3], 0.f));
                    v.z = pack2bf(fmaxf(acc[c + 4], 0.f), fmaxf(acc[c + 5], 0.f));
                    v.w = pack2bf(fmaxf(acc[c + 6], 0.f), fmaxf(acc[c + 7], 0.f));
                    *(uint4*)&orow[c] = v;
                }
            } else {
                uint2 v;
                v.x = pack2bf(fmaxf(acc[0], 0.f), fmaxf(acc[1], 0.f));
                v.y = pack2bf(fmaxf(acc[2], 0.f), fmaxf(acc[3], 0.f));
                *(uint2*)orow = v;
            }
        } else {
            float* orow = (float*)out + (size_t)dst * D + lane * DW;
#pragma unroll
            for (int c = 0; c < DW; c += 4) {
                float4 v = make_float4(fmaxf(acc[c + 0], 0.f), fmaxf(acc[c + 1], 0.f),
                                       fmaxf(acc[c + 2], 0.f), fmaxf(acc[c + 3], 0.f));
                *(float4*)&orow[c] = v;
            }
        }
    }
}

// ---------------- semantic attention tail ----------------

__global__ void softmax2_kernel(const float* __restrict__ score, float invN, float* __restrict__ w) {
    if (threadIdx.x == 0 && blockIdx.x == 0) {
        float s0 = score[0] * invN, s1 = score[1] * invN;
        float m = fmaxf(s0, s1);
        float e0 = expf(s0 - m), e1 = expf(s1 - m);
        float r = 1.f / (e0 + e1);
        w[0] = e0 * r;
        w[1] = e1 * r;
    }
}

__global__ void combine2_kernel(const float4* __restrict__ a, const float4* __restrict__ b,
                                const float* __restrict__ w, float4* __restrict__ o, int n4) {
    float w0 = w[0], w1 = w[1];
    for (int i = blockIdx.x * blockDim.x + threadIdx.x; i < n4; i += gridDim.x * blockDim.x) {
        float4 x = a[i], y = b[i];
        o[i] = make_float4(w0 * x.x + w1 * y.x, w0 * x.y + w1 * y.y,
                           w0 * x.z + w1 * y.z, w0 * x.w + w1 * y.w);
    }
}

// ---------------- host orchestration ----------------

extern "C" void kernel_launch(void* const* d_in, const int* in_sizes, int n_in,
                              void* d_out, int out_size, void* d_ws, size_t ws_size,
                              hipStream_t stream) {
    const float* x_a  = (const float*)d_in[0];
    const float* x_p  = (const float*)d_in[1];
    const float* W1   = (const float*)d_in[2];
    const float* b1   = (const float*)d_in[3];
    const float* att1 = (const float*)d_in[4];
    const float* kW1  = (const float*)d_in[5];
    const float* kb1  = (const float*)d_in[6];
    const float* q1   = (const float*)d_in[7];
    const float* W2   = (const float*)d_in[8];
    const float* b2   = (const float*)d_in[9];
    const float* att2 = (const float*)d_in[10];
    const float* kW2  = (const float*)d_in[11];
    const float* kb2  = (const float*)d_in[12];
    const float* q2   = (const float*)d_in[13];
    const void* e_ap  = d_in[14];
    const void* e_pa  = d_in[15];
    const void* e_aa  = d_in[16];
    float* out = (float*)d_out;

    size_t off = 0;
    auto ALLOC = [&](size_t nbytes) -> void* {
        void* p = (char*)d_ws + off;
        off += (nbytes + 255) & ~(size_t)255;
        return p;
    };
    float* bufA = (float*)ALLOC((size_t)NPAP * DHID * 4);  // h_p(bf16, lower) | x2_p(bf16, upper)
    float* bufB = (float*)ALLOC((size_t)NA * DHID * 4);    // h_a(bf16) -> h2a(bf16)
    float* bufC = (float*)ALLOC((size_t)NA * DHID * 4);    // o1(bf16) -> oa1|oa2(f32)
    float* bufD = (float*)ALLOC((size_t)NA * DHID * 4);    // o2(bf16) -> h2p(bf16)
    float* sa_w  = (float*)ALLOC((size_t)NA * 4);
    float* sa_pd = (float*)ALLOC((size_t)NA * 4);
    float* sa_as = (float*)ALLOC((size_t)NA * 4);
    float* sa_ad = (float*)ALLOC((size_t)NA * 4);
    float* sp_wd = (float*)ALLOC((size_t)NPAP * 4);
    float* sp_ps = (float*)ALLOC((size_t)NPAP * 4);
    int* cnt3    = (int*)ALLOC((size_t)(NPAP + 2 * NA + 8) * 4);
    int* scanpart = (int*)ALLOC(256 * 4);
    int* cursor3 = (int*)ALLOC((size_t)(NPAP + 2 * NA + 8) * 4);
    int* offs_ap = (int*)ALLOC((size_t)(NPAP + 1) * 4);
    int* offs_pa = (int*)ALLOC((size_t)(NA + 1) * 4);
    int* offs_aa = (int*)ALLOC((size_t)(NA + 1) * 4);
    int* eids_ap = (int*)ALLOC((size_t)EAP * 4);
    int* eids_pa = (int*)ALLOC((size_t)EPA * 4);
    int* eids_aa = (int*)ALLOC((size_t)EAA * 4);
    const size_t WTOT = 262144u * 3 + 131072u * 2 + 65536u;  // 1,114,112 u16
    u16* w_hi = (u16*)ALLOC(WTOT * 2);
    u16* w_lo = (u16*)ALLOC(WTOT * 2);
    float* score = (float*)ALLOC(8 * 4);
    float* wsem  = (float*)ALLOC(2 * 4);
    int* eflag   = (int*)ALLOC(4);
    if (off > ws_size) return;  // insufficient scratch -> visible failure

    const size_t oW1a = 0, oW1p = 262144, okW1 = 524288;
    const size_t oW2a = 786432, oW2p = 917504, okW2 = 1048576;

    int* cntA = cnt3;
    int* cntB = cnt3 + NPAP + 1;
    int* cntC = cntB + NA + 1;
    int* curA = cursor3;
    int* curB = cursor3 + NPAP + 1;
    int* curC = curB + NA + 1;
    const int CNT3N = NPAP + 2 * NA + 3;

    hipStream_t s = stream;

    detect_kernel<<<1, 256, 0, s>>>((const unsigned*)e_ap, 1024, eflag);

    // ---- one-shot weight conversion (all 6 matrices) ----
    auto conv_b = [&](const float* B_, int K, int N, size_t wo) {
        conv_bt_kernel<<<dim3(N / 32, K / 32), dim3(32, 8), 0, s>>>(B_, w_hi + wo, w_lo + wo, K, N);
    };
    conv_b(W1, DIN, DHID, oW1a);
    conv_b(W1 + (size_t)DIN * DHID, DIN, DHID, oW1p);
    conv_b(kW1, DHID, DHID, okW1);
    conv_b(W2, DHID, DOUT, oW2a);
    conv_b(W2 + (size_t)DHID * DOUT, DHID, DOUT, oW2p);
    conv_b(kW2, DOUT, DOUT, okW2);

    // ---- batched CSR build for all 3 edge types (parallel 3-phase scan) ----
    {
        const int ETOT = EAP + EPA + EAA;
        const int nblk = (CNT3N + 1023) / 1024;  // 196
        fill_u32_kernel<<<(CNT3N + 255) / 256, 256, 0, s>>>((unsigned*)cnt3, 0u, CNT3N);
        count3_kernel<<<(ETOT + 255) / 256, 256, 0, s>>>(e_ap, e_pa, e_aa, eflag, cntA, cntB, cntC);
        scanp1_kernel<<<nblk, 1024, 0, s>>>(cnt3, CNT3N, scanpart);
        scanp2_kernel<<<1, 1024, 0, s>>>(scanpart, nblk);
        scanp3_kernel<<<nblk, 1024, 0, s>>>(cnt3, CNT3N, scanpart,
                                            offs_ap, curA, offs_pa, curB, offs_aa, curC);
        scatter3_kernel<<<(ETOT + 255) / 256, 256, 0, s>>>(e_ap, e_pa, e_aa, eflag,
                                                           curA, curB, curC,
                                                           eids_ap, eids_pa, eids_aa);
    }

    auto gemm_proj_h = [&](const float* A_, size_t wo, const float* bias_, float* C_,
                           int M, int N, int K) {  // f32 A (RNE 2-pass), bf16 C
        int gx = N / 128;
        int nwg = gx * ((M + 127) / 128);
        mfma_gemm_2p_kernel<true><<<nwg, 256, 0, s>>>(A_,
            w_hi + wo, w_lo + wo, bias_, C_, M, N, K, gx);
    };
    auto gemm_proj_bfA_h = [&](const u16* A_, size_t wo, const float* bias_, float* C_,
                               int M, int N, int K) {  // bf16 A, bf16 C
        int gx = N / 128;
        int nwg = gx * ((M + 127) / 128);
        mfma_gemm_bfA_kernel<false, true><<<nwg, 256, 0, s>>>(A_, nullptr, nullptr,
            w_hi + wo, w_lo + wo, bias_, C_, M, N, K, gx);
    };
    auto gemm_proj_bfA_comb_h = [&](const u16* A_, const u16* A2_, const float* cw, size_t wo,
                                    const float* bias_, float* C_, int M, int N, int K) {
        int gx = N / 128;
        int nwg = gx * ((M + 127) / 128);
        mfma_gemm_bfA_kernel<true, true><<<nwg, 256, 0, s>>>(A_, A2_, cw,
            w_hi + wo, w_lo + wo, bias_, C_, M, N, K, gx);
    };
    auto gemm_score_b = [&](const void* A_, size_t wo, const float* bias_, int M, int N, int K,
                            const float* qv, float* sc) {  // bf16 A
        int gx = N / 128;
        int nwg = gx * ((M + 127) / 128);
        mfma_score1_kernel<true><<<nwg, 256, 0, s>>>(A_, w_hi + wo, bias_, M, N, K, qv, sc, gx);
    };
    auto gemm_score_f = [&](const void* A_, size_t wo, const float* bias_, int M, int N, int K,
                            const float* qv, float* sc) {  // f32 A
        int gx = N / 128;
        int nwg = gx * ((M + 127) / 128);
        mfma_score1_kernel<false><<<nwg, 256, 0, s>>>(A_, w_hi + wo, bias_, M, N, K, qv, sc, gx);
    };

    // ---------------- layer 1 (D = 512, h tables + agg outputs bf16) ----------------
    u16* h_a = (u16*)bufB;
    u16* h_p = (u16*)bufA;
    gemm_proj_h(x_a, oW1a, b1, (float*)h_a, NA, DHID, DIN);
    gemm_proj_h(x_p, oW1p, b1 + DHID, (float*)h_p, NPAP, DHID, DIN);

    {
        int ga = (NA + 3) / 4 < 4096 ? (NA + 3) / 4 : 4096;
        int gp = (NPAP + 3) / 4 < 4096 ? (NPAP + 3) / 4 : 4096;
        scores_kernel<4, true><<<ga, 256, 0, s>>>(h_a, NA, DHID,
            att1 + 0 * DHID, att1 + 3 * DHID, att1 + 4 * DHID, att1 + 5 * DHID,
            sa_w, sa_pd, sa_as, sa_ad);
        scores_kernel<2, true><<<gp, 256, 0, s>>>(h_p, NPAP, DHID,
            att1 + 1 * DHID, att1 + 2 * DHID, nullptr, nullptr,
            sp_wd, sp_ps, nullptr, nullptr);
    }

    u16* o1  = (u16*)bufC;   // out_a1, bf16
    u16* o2  = (u16*)bufD;   // out_a2, bf16
    u16* x2p = (u16*)bufA + (size_t)NPAP * DHID;  // out_p, bf16 (upper half of bufA)
    {
        int gw = (NA + 3) / 4;
        agg_fused_kernel<8, true, true><<<gw, 256, 0, s>>>(offs_pa, eids_pa, e_pa, eflag,
            sp_ps, sa_pd, h_p, o1, NA, EPA, DHID);
        agg_fused_kernel<8, true, true><<<gw, 256, 0, s>>>(offs_aa, eids_aa, e_aa, eflag,
            sa_as, sa_ad, h_a, o2, NA, EAA, DHID);
        int gw2 = (NPAP + 3) / 4;
        agg_fused_kernel<8, true, true><<<gw2, 256, 0, s>>>(offs_ap, eids_ap, e_ap, eflag,
            sa_w, sp_wd, h_a, x2p, NPAP, EAP, DHID);
    }

    // L1 semantic: scores + weights only (combine folded into the L2 a-projection)
    fill_u32_kernel<<<1, 64, 0, s>>>((unsigned*)score, 0u, 2);
    gemm_score_b(o1, okW1, kb1, NA, DHID, DHID, q1, &score[0]);
    gemm_score_b(o2, okW1, kb1, NA, DHID, DHID, q1, &score[1]);
    softmax2_kernel<<<1, 64, 0, s>>>(score, 1.f / (float)NA, wsem);

    // ---------------- layer 2 (D = 256, h2 tables bf16) ----------------
    u16* h2a = (u16*)bufB;   // h_a dead (last read: e_ap agg above)
    u16* h2p = (u16*)bufD;   // o2's last read is the COMB projection (stream-ordered)
    gemm_proj_bfA_comb_h(o1, o2, wsem, oW2a, b2, (float*)h2a, NA, DOUT, DHID);
    gemm_proj_bfA_h(x2p, oW2p, b2 + DOUT, (float*)h2p, NPAP, DOUT, DHID);

    {
        int ga = (NA + 3) / 4 < 4096 ? (NA + 3) / 4 : 4096;
        int gp = (NPAP + 3) / 4 < 4096 ? (NPAP + 3) / 4 : 4096;
        scores_kernel<3, true><<<ga, 256, 0, s>>>(h2a, NA, DOUT,
            att2 + 3 * DOUT, att2 + 4 * DOUT, att2 + 5 * DOUT, nullptr,
            sa_pd, sa_as, sa_ad, nullptr);
        scores_kernel<1, true><<<gp, 256, 0, s>>>(h2p, NPAP, DOUT,
            att2 + 2 * DOUT, nullptr, nullptr, nullptr,
            sp_ps, nullptr, nullptr, nullptr);
    }

    float* oa1 = bufC;                       // o1 dead after COMB projection
    float* oa2 = bufC + (size_t)NA * DOUT;
    {
        int gw = (NA + 3) / 4;
        agg_fused_kernel<4, true, false><<<gw, 256, 0, s>>>(offs_pa, eids_pa, e_pa, eflag,
            sp_ps, sa_pd, h2p, oa1, NA, EPA, DOUT);
        agg_fused_kernel<4, true, false><<<gw, 256, 0, s>>>(offs_aa, eids_aa, e_aa, eflag,
            sa_as, sa_ad, h2a, oa2, NA, EAA, DOUT);
    }

    // L2 semantic (final): scores + combine into out
    fill_u32_kernel<<<1, 64, 0, s>>>((unsigned*)score, 0u, 2);
    gemm_score_f(oa1, okW2, kb2, NA, DOUT, DOUT, q2, &score[0]);
    gemm_score_f(oa2, okW2, kb2, NA, DOUT, DOUT, q2, &score[1]);
    softmax2_kernel<<<1, 64, 0, s>>>(score, 1.f / (float)NA, wsem);
    combine2_kernel<<<2048, 256, 0, s>>>((const float4*)oa1, (const float4*)oa2, wsem,
                                         (float4*)out, NA * DOUT / 4);
}